// Round 24
// baseline (925.055 us; speedup 1.0000x reference)
//
#include <hip/hip_runtime.h>
#include <hip/hip_bf16.h>
#include <math.h>

typedef _Float16 f16;
typedef f16 f16x8 __attribute__((ext_vector_type(8)));
typedef float f32x4 __attribute__((ext_vector_type(4)));

#define NPT 1365
#define HD 512
#define NINT 341   // internal nodes per tree (256+64+16+4+1)
#define IOU_LDS (2*128*64*2 + 2*192*64*2)   // 81920 B -> 2 blocks/CU
#define G128_LDS (2*128*64*2 + 2*128*64*2)  // 65536 B -> 2 blocks/CU

__device__ __forceinline__ float frcp(float x){ return __builtin_amdgcn_rcpf(x); }
__device__ __forceinline__ float sigm(float x){ return frcp(1.0f+__expf(-x)); }
__device__ __forceinline__ float ftanh(float x){
  float e=__expf(2.f*fabsf(x));
  float t=1.f-2.f*frcp(e+1.f);
  return copysignf(t,x);
}

__device__ __forceinline__ void gll16(const void* g, void* l){
  __builtin_amdgcn_global_load_lds((const __attribute__((address_space(1))) void*)g,
                                   (__attribute__((address_space(3))) void*)l, 16, 0, 0);
}

// XCD-chunked bijection: phys%8 = XCD; each XCD gets a contiguous y-range with all x.
__device__ __forceinline__ void xcd_map(int phys, int nb, int xdim, int& x, int& my){
  int ytiles = nb / xdim;
  if((ytiles & 7)==0){
    int k = phys & 7, i = phys >> 3;
    my = k * (ytiles >> 3) + i / xdim;
    x  = i % xdim;
  }else{
    x  = phys % xdim;
    my = phys / xdim;
  }
}

// ================= fused prep: all elementwise weight/feature conversions =================
__global__ void k_prep(const float* __restrict__ features,
                       const float* __restrict__ W_iou, const float* __restrict__ U_iou,
                       const float* __restrict__ W_f, const float* __restrict__ U_f,
                       const float* __restrict__ Wsf, const float* __restrict__ Wsd2,
                       f16* __restrict__ fx, f16* __restrict__ WilL, f16* __restrict__ WilI,
                       f16* __restrict__ Wcat2, f16* __restrict__ Wfc, f16* __restrict__ Ufc,
                       float* __restrict__ tmp4, size_t nfeat8)
{
  size_t gid=(size_t)blockIdx.x*256+threadIdx.x;
  const size_t n0=nfeat8;
  const size_t n1=n0+(size_t)1536*768;
  const size_t n2=n1+(size_t)1536*1280;
  const size_t n3=n2+(size_t)1536*1280;
  const size_t n4=n3+(size_t)512*768/8;
  const size_t n5=n4+(size_t)512*512/8;
  const size_t n6=n5+4096;
  if(gid<n0){
    size_t i=gid;
    const float4* sp=(const float4*)(features+i*8);
    float4 a=sp[0], b=sp[1];
    float v[8]={a.x,a.y,a.z,a.w,b.x,b.y,b.z,b.w};
    f16x8 h;
    #pragma unroll
    for(int e=0;e<8;++e) h[e]=(f16)v[e];
    *(f16x8*)(fx+i*8)=h;
  }else if(gid<n1){
    size_t i=gid-n0;
    int rp=(int)(i/768); int k=(int)(i-(size_t)rp*768);
    int f=rp>>4, rr=rp&15;
    int orig=(f%3)*512+(f/3)*16+rr;
    WilL[i]=(f16)W_iou[(size_t)orig*768+k];
  }else if(gid<n2){
    size_t i=gid-n1;
    int rp=(int)(i/1280); int k=(int)(i-(size_t)rp*1280);
    int f=rp>>4, rr=rp&15;
    int orig=(f%3)*512+(f/3)*16+rr;
    float v=(k<768)? W_iou[(size_t)orig*768+k] : U_iou[(size_t)orig*512+(k-768)];
    WilI[i]=(f16)v;
  }else if(gid<n3){
    size_t i=gid-n2;
    int r=(int)(i/1280); int k=(int)(i-(size_t)r*1280);
    float v=(k<768)? W_iou[(size_t)r*768+k] : U_iou[(size_t)r*512+(k-768)];
    Wcat2[i]=(f16)v;
  }else if(gid<n4){
    size_t i=gid-n3;
    const float4* sp=(const float4*)(W_f+i*8);
    float4 a=sp[0], b=sp[1];
    float v[8]={a.x,a.y,a.z,a.w,b.x,b.y,b.z,b.w};
    f16x8 h;
    #pragma unroll
    for(int e=0;e<8;++e) h[e]=(f16)v[e];
    *(f16x8*)(Wfc+i*8)=h;
  }else if(gid<n5){
    size_t i=gid-n4;
    const float4* sp=(const float4*)(U_f+i*8);
    float4 a=sp[0], b=sp[1];
    float v[8]={a.x,a.y,a.z,a.w,b.x,b.y,b.z,b.w};
    f16x8 h;
    #pragma unroll
    for(int e=0;e<8;++e) h[e]=(f16)v[e];
    *(f16x8*)(Ufc+i*8)=h;
  }else if(gid<n6){
    int idx=(int)(gid-n5);
    int j=idx>>10, e=idx&1023;
    float s=0.f;
    #pragma unroll 8
    for(int d=0;d<512;++d) s+=Wsf[j*512+d]*Wsd2[(size_t)d*1024+e];
    tmp4[(size_t)j*1024+e]=s;
  }
}

// ---------------- Wy[j][c] = Wsf[j][c] + sum_e tmp[j][e] * W_sd[e][c]  (4 x 512) ----------------
__global__ void k_wy2(const float* __restrict__ Wsf, const float* __restrict__ tmp,
                      const float* __restrict__ Wsd, float* __restrict__ Wy){
  int idx=blockIdx.x*256+threadIdx.x;
  if(idx>=2048) return;
  int j=idx>>9, c=idx&511;
  float s=Wsf[j*512+c];
  #pragma unroll 8
  for(int e=0;e<1024;++e) s+=tmp[j*1024+e]*Wsd[(size_t)e*512+c];
  Wy[(size_t)j*512+c]=s;
}

// ================= fused leaf iou (2 M-tiles/block) + XWf =================
__global__ __launch_bounds__(256,2)
void k_leafxwf(const f16* __restrict__ fx, const f16* __restrict__ WilL,
               const float* __restrict__ bias, f16* __restrict__ h16,
               float* __restrict__ cbuf,
               const f16* __restrict__ Wfc, float* __restrict__ XWf,
               int nbLeaf, int Mtot)
{
  extern __shared__ char sm[];
  const int tid=threadIdx.x;
  const int w=tid>>6, lane=tid&63;
  const int lr=lane&15, lg=lane>>4;
  const unsigned swz=8u*((unsigned)(lane&7)^(unsigned)(lane>>3));

  if((int)blockIdx.x < nbLeaf){
    // ---------- leaf iou: 2 x (128 x 192), K=768, NT=12 ----------
    char* Abase=sm;
    char* Bbase=sm+32768;
    int x, my;
    xcd_map(blockIdx.x, nbLeaf, 8, x, my);
    const int NT=12;

    unsigned bofs[6];
    #pragma unroll
    for(int i=0;i<6;++i){
      int r=x*192+w*48+i*8+(lane>>3);
      bofs[i]=(unsigned)r*768u;
    }
    const int wr=(w>>1)*64;
    const int wcF=(w&1)*6;

    unsigned fofs[4];
    f32x4 acc[4][6];

    auto STAGE=[&](int buf, int t){
      const unsigned kofs=(unsigned)t*64u+swz;
      char* Ad=Abase+(size_t)buf*16384;
      #pragma unroll
      for(int i=0;i<4;++i)
        gll16(fx+fofs[i]+kofs, Ad+(w*32+i*8)*128);
      char* Bd=Bbase+(size_t)buf*24576;
      #pragma unroll
      for(int i=0;i<6;++i)
        gll16(WilL+bofs[i]+kofs, Bd+(w*48+i*8)*128);
    };

    auto COMPUTE=[&](int cur){
      const char* Ab=Abase+(size_t)cur*16384;
      const char* Bb=Bbase+(size_t)cur*24576;
      #pragma unroll
      for(int ks=0;ks<2;++ks){
        const unsigned cb=((unsigned)(ks*64+lg*16)) ^ ((unsigned)(lr&7)<<4);
        f16x8 av[4], bv[6];
        #pragma unroll
        for(int mi=0;mi<4;++mi)
          av[mi]=*(const f16x8*)(Ab+(unsigned)(wr+mi*16+lr)*128u+cb);
        #pragma unroll
        for(int ni=0;ni<6;++ni)
          bv[ni]=*(const f16x8*)(Bb+(unsigned)((wcF+ni)*16+lr)*128u+cb);
        __builtin_amdgcn_s_setprio(1);
        #pragma unroll
        for(int ni=0;ni<6;++ni)
          #pragma unroll
          for(int mi=0;mi<4;++mi)
            acc[mi][ni]=__builtin_amdgcn_mfma_f32_16x16x32_f16(av[mi],bv[ni],acc[mi][ni],0,0,0);
        __builtin_amdgcn_s_setprio(0);
      }
    };

    for(int it=0; it<2; ++it){
      const int m0=my*256+it*128;
      #pragma unroll
      for(int i=0;i<4;++i){
        int r=w*32+i*8+(lane>>3);
        int m=m0+r;
        int t_=m>>10, j=m-(t_<<10);
        fofs[i]=(unsigned)(((size_t)t_*NPT+j)*768);
      }
      #pragma unroll
      for(int mi=0;mi<4;++mi)
        #pragma unroll
        for(int ni=0;ni<6;++ni) acc[mi][ni]=(f32x4){0.f,0.f,0.f,0.f};

      STAGE(0,0);
      STAGE(1,1);
      asm volatile("s_waitcnt vmcnt(10)" ::: "memory");
      __builtin_amdgcn_s_barrier();
      __builtin_amdgcn_sched_barrier(0);

      for(int t=0;t<NT;++t){
        COMPUTE(t&1);
        if(t+1<NT){
          __builtin_amdgcn_sched_barrier(0);
          __builtin_amdgcn_s_barrier();
          __builtin_amdgcn_sched_barrier(0);
          if(t+2<NT){
            STAGE(t&1, t+2);
            asm volatile("s_waitcnt vmcnt(10)" ::: "memory");
          }else{
            asm volatile("s_waitcnt vmcnt(0)" ::: "memory");
          }
          __builtin_amdgcn_s_barrier();
          __builtin_amdgcn_sched_barrier(0);
        }
      }

      #pragma unroll
      for(int mi=0;mi<4;++mi){
        #pragma unroll
        for(int cg=0;cg<2;++cg){
          const int col = x*64 + ((w&1)*2+cg)*16 + lr;
          const float bi=bias[col], bo=bias[col+512], bu=bias[col+1024];
          #pragma unroll
          for(int r=0;r<4;++r){
            const int mm=m0+wr+mi*16+lg*4+r;
            float iv=acc[mi][3*cg+0][r]+bi;
            float ov=acc[mi][3*cg+1][r]+bo;
            float uv=acc[mi][3*cg+2][r]+bu;
            float cn=sigm(iv)*ftanh(uv);
            float hn=sigm(ov)*ftanh(cn);
            const int tt=mm>>10, jj=mm-(tt<<10);
            const size_t nd=((size_t)tt*NPT+jj)*HD+col;
            cbuf[nd]=cn;
            h16[nd]=(f16)hn;
          }
        }
      }
      if(it==0){
        __builtin_amdgcn_s_barrier();   // all waves done with LDS before tile-2 staging
        __builtin_amdgcn_sched_barrier(0);
      }
    }
  } else {
    // ---------- XWf: 128x128, K=768, NT=12 ----------
    char* Abase=sm;
    char* Bbase=sm+32768;
    int phys=(int)blockIdx.x-nbLeaf;
    int nb=(int)gridDim.x-nbLeaf;
    int xb, my;
    xcd_map(phys, nb, 4, xb, my);
    const int m0=my*128, n0=xb*128;
    const int NT=12;

    unsigned fofs[4];
    #pragma unroll
    for(int i=0;i<4;++i){
      int r=w*32+i*8+(lane>>3);
      int m=m0+r; if(m>=Mtot) m=Mtot-1;
      int t=m/NINT; int j=1024+(m-t*NINT);
      fofs[i]=(unsigned)(((size_t)t*NPT+j)*768);
    }
    unsigned bofs[4];
    #pragma unroll
    for(int i=0;i<4;++i){
      int r=n0+w*32+i*8+(lane>>3);
      bofs[i]=(unsigned)r*768u;
    }

    f32x4 acc[4][4];
    #pragma unroll
    for(int mi=0;mi<4;++mi)
      #pragma unroll
      for(int ni=0;ni<4;++ni) acc[mi][ni]=(f32x4){0.f,0.f,0.f,0.f};

    const int wr=(w>>1)*64, wc=(w&1)*64;

    auto STAGE=[&](int buf, int t){
      const unsigned ak=(unsigned)t*64u+swz;
      char* Ad=Abase+(size_t)buf*16384;
      #pragma unroll
      for(int i=0;i<4;++i)
        gll16(fx+fofs[i]+ak, Ad+(w*32+i*8)*128);
      char* Bd=Bbase+(size_t)buf*16384;
      #pragma unroll
      for(int i=0;i<4;++i)
        gll16(Wfc+bofs[i]+ak, Bd+(w*32+i*8)*128);
    };

    auto COMPUTE=[&](int cur){
      const char* Ab=Abase+(size_t)cur*16384;
      const char* Bb=Bbase+(size_t)cur*16384;
      #pragma unroll
      for(int ks=0;ks<2;++ks){
        const unsigned cb=((unsigned)(ks*64+lg*16)) ^ ((unsigned)(lr&7)<<4);
        f16x8 av[4], bv[4];
        #pragma unroll
        for(int mi=0;mi<4;++mi)
          av[mi]=*(const f16x8*)(Ab+(unsigned)(wr+mi*16+lr)*128u+cb);
        #pragma unroll
        for(int ni=0;ni<4;++ni)
          bv[ni]=*(const f16x8*)(Bb+(unsigned)((wc+ni*16)+lr)*128u+cb);
        __builtin_amdgcn_s_setprio(1);
        #pragma unroll
        for(int ni=0;ni<4;++ni)
          #pragma unroll
          for(int mi=0;mi<4;++mi)
            acc[mi][ni]=__builtin_amdgcn_mfma_f32_16x16x32_f16(av[mi],bv[ni],acc[mi][ni],0,0,0);
        __builtin_amdgcn_s_setprio(0);
      }
    };

    STAGE(0,0);
    STAGE(1,1);
    asm volatile("s_waitcnt vmcnt(8)" ::: "memory");
    __builtin_amdgcn_s_barrier();
    __builtin_amdgcn_sched_barrier(0);

    for(int t=0;t<NT;++t){
      COMPUTE(t&1);
      if(t+1<NT){
        __builtin_amdgcn_sched_barrier(0);
        __builtin_amdgcn_s_barrier();
        __builtin_amdgcn_sched_barrier(0);
        if(t+2<NT){
          STAGE(t&1, t+2);
          asm volatile("s_waitcnt vmcnt(8)" ::: "memory");
        }else{
          asm volatile("s_waitcnt vmcnt(0)" ::: "memory");
        }
        __builtin_amdgcn_s_barrier();
        __builtin_amdgcn_sched_barrier(0);
      }
    }

    #pragma unroll
    for(int mi=0;mi<4;++mi){
      #pragma unroll
      for(int ni=0;ni<4;++ni){
        const int col=n0+wc+ni*16+lr;
        #pragma unroll
        for(int r=0;r<4;++r){
          const int mm=m0+wr+mi*16+lg*4+r;
          if(mm<Mtot) XWf[(size_t)mm*512+col]=acc[mi][ni][r];
        }
      }
    }
  }
}

// ================= internal iou GEMM: 2 x (128 x 192), f16, XCD-chunked =================
__global__ __launch_bounds__(256,2)
void k_iou128p(const f16* __restrict__ fx, const f16* __restrict__ hs16,
               const f16* __restrict__ Wil, const float* __restrict__ bias,
               const float* __restrict__ csum, f16* __restrict__ h16,
               float* __restrict__ cbuf,
               int start_n, int shift)
{
  extern __shared__ char sm[];                 // A: 2x16384, B: 2x24576
  char* Abase=sm;
  char* Bbase=sm+32768;
  const int tid=threadIdx.x;
  const int w=tid>>6, lane=tid&63;
  int x, my;
  xcd_map(blockIdx.x, gridDim.x, 8, x, my);
  const int K=1280;
  const int NT=20;

  unsigned bofs[6];
  #pragma unroll
  for(int i=0;i<6;++i){
    int r=x*192+w*48+i*8+(lane>>3);
    bofs[i]=(unsigned)r*(unsigned)K;
  }
  const unsigned swz=8u*((unsigned)(lane&7)^(unsigned)(lane>>3));
  const int wr=(w>>1)*64;
  const int wcF=(w&1)*6;
  const int lr=lane&15, lg=lane>>4;

  unsigned fofs[4], hofs[4];
  f32x4 acc[4][6];

  auto STAGE=[&](int buf, int t){
    const f16* base; int kt; bool useF;
    if(t<12){ base=fx;   kt=t;    useF=true;  }
    else    { base=hs16; kt=t-12; useF=false; }
    const unsigned kofs=(unsigned)kt*64u+swz;
    char* Ad=Abase+(size_t)buf*16384;
    #pragma unroll
    for(int i=0;i<4;++i){
      const f16* g=base+(useF?fofs[i]:hofs[i])+kofs;
      gll16(g, Ad+(w*32+i*8)*128);
    }
    const unsigned bk=(unsigned)t*64u+swz;
    char* Bd=Bbase+(size_t)buf*24576;
    #pragma unroll
    for(int i=0;i<6;++i){
      gll16(Wil+bofs[i]+bk, Bd+(w*48+i*8)*128);
    }
  };

  auto COMPUTE=[&](int cur){
    const char* Ab=Abase+(size_t)cur*16384;
    const char* Bb=Bbase+(size_t)cur*24576;
    #pragma unroll
    for(int ks=0;ks<2;++ks){
      const unsigned cb=((unsigned)(ks*64+lg*16)) ^ ((unsigned)(lr&7)<<4);
      f16x8 av[4], bv[6];
      #pragma unroll
      for(int mi=0;mi<4;++mi)
        av[mi]=*(const f16x8*)(Ab+(unsigned)(wr+mi*16+lr)*128u+cb);
      #pragma unroll
      for(int ni=0;ni<6;++ni)
        bv[ni]=*(const f16x8*)(Bb+(unsigned)((wcF+ni)*16+lr)*128u+cb);
      __builtin_amdgcn_s_setprio(1);
      #pragma unroll
      for(int ni=0;ni<6;++ni)
        #pragma unroll
        for(int mi=0;mi<4;++mi)
          acc[mi][ni]=__builtin_amdgcn_mfma_f32_16x16x32_f16(av[mi],bv[ni],acc[mi][ni],0,0,0);
      __builtin_amdgcn_s_setprio(0);
    }
  };

  for(int it=0; it<2; ++it){
    const int m0=my*256+it*128;
    #pragma unroll
    for(int i=0;i<4;++i){
      int r=w*32+i*8+(lane>>3);
      int m=m0+r;
      int t_=m>>shift, j=m-(t_<<shift);
      fofs[i]=(unsigned)(((size_t)t_*NPT+start_n+j)*768);
      hofs[i]=(unsigned)m*512u;
    }
    #pragma unroll
    for(int mi=0;mi<4;++mi)
      #pragma unroll
      for(int ni=0;ni<6;++ni) acc[mi][ni]=(f32x4){0.f,0.f,0.f,0.f};

    STAGE(0,0);
    STAGE(1,1);
    asm volatile("s_waitcnt vmcnt(10)" ::: "memory");
    __builtin_amdgcn_s_barrier();
    __builtin_amdgcn_sched_barrier(0);

    for(int t=0;t<NT;++t){
      COMPUTE(t&1);
      if(t+1<NT){
        __builtin_amdgcn_sched_barrier(0);
        __builtin_amdgcn_s_barrier();
        __builtin_amdgcn_sched_barrier(0);
        if(t+2<NT){
          STAGE(t&1, t+2);
          asm volatile("s_waitcnt vmcnt(10)" ::: "memory");
        }else{
          asm volatile("s_waitcnt vmcnt(0)" ::: "memory");
        }
        __builtin_amdgcn_s_barrier();
        __builtin_amdgcn_sched_barrier(0);
      }
    }

    #pragma unroll
    for(int mi=0;mi<4;++mi){
      #pragma unroll
      for(int cg=0;cg<2;++cg){
        const int col = x*64 + ((w&1)*2+cg)*16 + lr;
        const float bi=bias[col], bo=bias[col+512], bu=bias[col+1024];
        #pragma unroll
        for(int r=0;r<4;++r){
          const int mm=m0+wr+mi*16+lg*4+r;
          float iv=acc[mi][3*cg+0][r]+bi;
          float ov=acc[mi][3*cg+1][r]+bo;
          float uv=acc[mi][3*cg+2][r]+bu;
          float cn=sigm(iv)*ftanh(uv);
          cn+=csum[(size_t)mm*HD+col];
          float hn=sigm(ov)*ftanh(cn);
          const int tt=mm>>shift, jj=mm-(tt<<shift);
          const size_t nd=((size_t)tt*NPT+start_n+jj)*HD+col;
          cbuf[nd]=cn;
          h16[nd]=(f16)hn;
        }
      }
    }
    if(it==0){
      __builtin_amdgcn_s_barrier();
      __builtin_amdgcn_sched_barrier(0);
    }
  }
}

// ---------------- old 64-tile iou (level 5 only, P=64; K=1280 gate-major layout, f16) ----------------
__global__ __launch_bounds__(256)
void k_iou(const f16* __restrict__ fx, const f16* __restrict__ hs16,
           const f16* __restrict__ Wcat, const float* __restrict__ bias,
           const float* __restrict__ csum, f16* __restrict__ h16,
           float* __restrict__ cbuf,
           int start_n, int shift, int K, int KB)
{
  __shared__ f16 As[64][40];
  __shared__ f16 Bs[3][64][40];
  const int tid=threadIdx.x;
  const int m0=blockIdx.x*64, n0=blockIdx.y*64;
  const int srow=tid>>2, skc=(tid&3)*8;
  const int m=m0+srow;
  const int t=m>>shift, j=m-(t<<shift);
  const size_t frow=((size_t)t*NPT+start_n+j)*768;
  const f16* aF=fx+frow;
  const f16* aH=hs16+(size_t)m*HD;
  const f16* bp0=Wcat+(size_t)(n0+srow)*KB;
  const f16* bp1=Wcat+(size_t)(512+n0+srow)*KB;
  const f16* bp2=Wcat+(size_t)(1024+n0+srow)*KB;

  f32x4 acc[3][2][2];
  #pragma unroll
  for(int g=0;g<3;++g)
    #pragma unroll
    for(int mi=0;mi<2;++mi)
      #pragma unroll
      for(int ni=0;ni<2;++ni) acc[g][mi][ni]=(f32x4){0.f,0.f,0.f,0.f};

  const int w=tid>>6, lane=tid&63;
  const int wr=(w>>1)*32, wc=(w&1)*32;
  const int lr=lane&15, lg=lane>>4;

  for(int k0=0;k0<K;k0+=32){
    const f16* ap = (k0<768)? (aF+k0) : (aH+(k0-768));
    *(f16x8*)&As[srow][skc]=*(const f16x8*)(ap+skc);
    *(f16x8*)&Bs[0][srow][skc]=*(const f16x8*)(bp0+k0+skc);
    *(f16x8*)&Bs[1][srow][skc]=*(const f16x8*)(bp1+k0+skc);
    *(f16x8*)&Bs[2][srow][skc]=*(const f16x8*)(bp2+k0+skc);
    __syncthreads();
    f16x8 a0=*(f16x8*)&As[wr+lr][lg*8];
    f16x8 a1=*(f16x8*)&As[wr+16+lr][lg*8];
    #pragma unroll
    for(int g=0;g<3;++g){
      #pragma unroll
      for(int ni=0;ni<2;++ni){
        f16x8 bv=*(f16x8*)&Bs[g][wc+ni*16+lr][lg*8];
        acc[g][0][ni]=__builtin_amdgcn_mfma_f32_16x16x32_f16(a0,bv,acc[g][0][ni],0,0,0);
        acc[g][1][ni]=__builtin_amdgcn_mfma_f32_16x16x32_f16(a1,bv,acc[g][1][ni],0,0,0);
      }
    }
    __syncthreads();
  }

  #pragma unroll
  for(int mi=0;mi<2;++mi){
    #pragma unroll
    for(int ni=0;ni<2;++ni){
      const int col=n0+wc+ni*16+lr;
      const float bi=bias[col], bo=bias[col+512], bu=bias[col+1024];
      #pragma unroll
      for(int r=0;r<4;++r){
        const int mm=m0+wr+mi*16+lg*4+r;
        float iv=acc[0][mi][ni][r]+bi;
        float ov=acc[1][mi][ni][r]+bo;
        float uv=acc[2][mi][ni][r]+bu;
        float cn=sigm(iv)*ftanh(uv);
        cn+=csum[(size_t)mm*HD+col];
        float hn=sigm(ov)*ftanh(cn);
        const int tt=mm>>shift, jj=mm-(tt<<shift);
        const size_t nd=((size_t)tt*NPT+start_n+jj)*HD+col;
        cbuf[nd]=cn;
        h16[nd]=(f16)hn;
      }
    }
  }
}

// ================= Uh forget-gate: pipelined 128x128 (NT=8, f16) + fused csum/hsum =================
__global__ __launch_bounds__(256,2)
void k_uh128p(const f16* __restrict__ h16,
              const f16* __restrict__ Ufc, const float* __restrict__ bias,
              const float* __restrict__ XWf, const float* __restrict__ cbuf,
              float* __restrict__ csum, f16* __restrict__ hs16,
              int start_ch, int lc, int xwoff)
{
  extern __shared__ char sm[];     // A: 2x16384, B: 2x16384
  char* Abase=sm;
  char* Bbase=sm+32768;
  const int tid=threadIdx.x;
  const int w=tid>>6, lane=tid&63;
  int xb, my;
  xcd_map(blockIdx.x, gridDim.x, 4, xb, my);
  const int e0=my*128, n0=xb*128;
  const int NT=8;

  unsigned hofs[4];
  #pragma unroll
  for(int i=0;i<4;++i){
    int r=w*32+i*8+(lane>>3);
    int e=e0+r;
    int t=e>>lc, ei=e-(t<<lc);
    hofs[i]=(unsigned)(((size_t)t*NPT+start_ch+ei)*HD);
  }
  unsigned bofs[4];
  #pragma unroll
  for(int i=0;i<4;++i){
    int r=n0+w*32+i*8+(lane>>3);
    bofs[i]=(unsigned)r*512u;
  }
  const unsigned swz=8u*((unsigned)(lane&7)^(unsigned)(lane>>3));

  f32x4 acc[4][4];
  #pragma unroll
  for(int mi=0;mi<4;++mi)
    #pragma unroll
    for(int ni=0;ni<4;++ni) acc[mi][ni]=(f32x4){0.f,0.f,0.f,0.f};

  const int wr=(w>>1)*64, wc=(w&1)*64;
  const int lr=lane&15, lg=lane>>4;

  auto STAGE=[&](int buf, int t){
    const unsigned ak=(unsigned)t*64u+swz;
    char* Ad=Abase+(size_t)buf*16384;
    #pragma unroll
    for(int i=0;i<4;++i)
      gll16(h16+hofs[i]+ak, Ad+(w*32+i*8)*128);
    char* Bd=Bbase+(size_t)buf*16384;
    #pragma unroll
    for(int i=0;i<4;++i)
      gll16(Ufc+bofs[i]+ak, Bd+(w*32+i*8)*128);
  };

  auto COMPUTE=[&](int cur){
    const char* Ab=Abase+(size_t)cur*16384;
    const char* Bb=Bbase+(size_t)cur*16384;
    #pragma unroll
    for(int ks=0;ks<2;++ks){
      const unsigned cb=((unsigned)(ks*64+lg*16)) ^ ((unsigned)(lr&7)<<4);
      f16x8 av[4], bv[4];
      #pragma unroll
      for(int mi=0;mi<4;++mi)
        av[mi]=*(const f16x8*)(Ab+(unsigned)(wr+mi*16+lr)*128u+cb);
      #pragma unroll
      for(int ni=0;ni<4;++ni)
        bv[ni]=*(const f16x8*)(Bb+(unsigned)((wc+ni*16)+lr)*128u+cb);
      __builtin_amdgcn_s_setprio(1);
      #pragma unroll
      for(int ni=0;ni<4;++ni)
        #pragma unroll
        for(int mi=0;mi<4;++mi)
          acc[mi][ni]=__builtin_amdgcn_mfma_f32_16x16x32_f16(av[mi],bv[ni],acc[mi][ni],0,0,0);
      __builtin_amdgcn_s_setprio(0);
    }
  };

  STAGE(0,0);
  STAGE(1,1);
  asm volatile("s_waitcnt vmcnt(8)" ::: "memory");
  __builtin_amdgcn_s_barrier();
  __builtin_amdgcn_sched_barrier(0);

  for(int t=0;t<NT;++t){
    COMPUTE(t&1);
    if(t+1<NT){
      __builtin_amdgcn_sched_barrier(0);
      __builtin_amdgcn_s_barrier();
      __builtin_amdgcn_sched_barrier(0);
      if(t+2<NT){
        STAGE(t&1, t+2);
        asm volatile("s_waitcnt vmcnt(8)" ::: "memory");
      }else{
        asm volatile("s_waitcnt vmcnt(0)" ::: "memory");
      }
      __builtin_amdgcn_s_barrier();
      __builtin_amdgcn_sched_barrier(0);
    }
  }

  #pragma unroll
  for(int mi=0;mi<4;++mi){
    const int ebase=e0+wr+mi*16+lg*4;
    const int tt=ebase>>lc, eib=ebase-(tt<<lc);
    const int inode=tt*NINT + xwoff + (eib>>2);
    const int par=ebase>>2;
    #pragma unroll
    for(int ni=0;ni<4;++ni){
      const int col=n0+wc+ni*16+lr;
      const float base=bias[col]+XWf[(size_t)inode*512+col];
      const size_t chbase=((size_t)tt*NPT+start_ch+eib)*HD+col;
      float s=0.f, hsv=0.f;
      #pragma unroll
      for(int r=0;r<4;++r){
        const size_t ci=chbase+(size_t)r*HD;
        float fv=sigm(acc[mi][ni][r]+base);
        s+=fv*cbuf[ci];
        hsv+=(float)h16[ci];
      }
      csum[(size_t)par*HD+col]=s;
      hs16[(size_t)par*HD+col]=(f16)hsv;
    }
  }
}

// ---------------- final heads: h_st softmax (+root blocks appended) ----------------
__global__ __launch_bounds__(256)
void k_final2(const f16* __restrict__ h16,
              const float* __restrict__ Wy, const float* __restrict__ gamma,
              const float* __restrict__ beta, float* __restrict__ out0,
              const float* __restrict__ Wff, float* __restrict__ out1,
              int Nn, int nbMain)
{
  const int tid=threadIdx.x;
  if((int)blockIdx.x < nbMain){
    const int gtid=blockIdx.x*256+tid;
    const int node=gtid>>6, lane=gtid&63;
    if(node>=Nn) return;
    const size_t base=(size_t)node*HD+lane*8;
    f16x8 hv=*(const f16x8*)(h16+base);
    float hf[8];
    #pragma unroll
    for(int e=0;e<8;++e) hf[e]=(float)hv[e];
    float y[4];
    #pragma unroll
    for(int jj=0;jj<4;++jj){
      const float* wp=Wy+jj*HD+lane*8;
      float s=0.f;
      #pragma unroll
      for(int e=0;e<8;++e) s+=hf[e]*wp[e];
      #pragma unroll
      for(int off=32;off>=1;off>>=1) s+=__shfl_xor(s,off,64);
      y[jj]=s;
    }
    if(lane==0){
      float mu=0.25f*(y[0]+y[1]+y[2]+y[3]);
      float var=0.f;
      #pragma unroll
      for(int jj=0;jj<4;++jj){ float d=y[jj]-mu; var+=d*d; }
      var*=0.25f;
      float rs=rsqrtf(var+1e-6f);
      float z[4], zmax=-1e30f;
      #pragma unroll
      for(int jj=0;jj<4;++jj){ z[jj]=(y[jj]-mu)*rs*gamma[jj]+beta[jj]; zmax=fmaxf(zmax,z[jj]); }
      float es=0.f;
      #pragma unroll
      for(int jj=0;jj<4;++jj){ z[jj]=__expf(z[jj]-zmax); es+=z[jj]; }
      float inv=frcp(es);
      #pragma unroll
      for(int jj=0;jj<4;++jj) out0[(size_t)node*4+jj]=z[jj]*inv;
    }
  } else {
    const int gtid=((int)blockIdx.x-nbMain)*256+tid;
    const int tt=gtid>>6, lane=gtid&63;
    if(tt>=64) return;
    const size_t base=((size_t)tt*NPT+1364)*HD+lane*8;
    f16x8 hv=*(const f16x8*)(h16+base);
    float hf[8];
    #pragma unroll
    for(int e=0;e<8;++e) hf[e]=(float)hv[e];
    float y[4];
    #pragma unroll
    for(int jj=0;jj<4;++jj){
      const float* wp=Wff+jj*HD+lane*8;
      float s=0.f;
      #pragma unroll
      for(int e=0;e<8;++e) s+=hf[e]*wp[e];
      #pragma unroll
      for(int off=32;off>=1;off>>=1) s+=__shfl_xor(s,off,64);
      y[jj]=s;
    }
    if(lane==0){
      float zmax=fmaxf(fmaxf(y[0],y[1]),fmaxf(y[2],y[3]));
      float es=0.f, z[4];
      #pragma unroll
      for(int jj=0;jj<4;++jj){ z[jj]=__expf(y[jj]-zmax); es+=z[jj]; }
      float inv=frcp(es);
      #pragma unroll
      for(int jj=0;jj<4;++jj) out1[(size_t)tt*4+jj]=z[jj]*inv;
    }
  }
}

extern "C" void kernel_launch(void* const* d_in, const int* in_sizes, int n_in,
                              void* d_out, int out_size, void* d_ws, size_t ws_size,
                              hipStream_t stream)
{
  const float* features=(const float*)d_in[0];
  const float* W_iou=(const float*)d_in[6];
  const float* b_iou=(const float*)d_in[7];
  const float* U_iou=(const float*)d_in[8];
  const float* W_f  =(const float*)d_in[9];
  const float* b_f  =(const float*)d_in[10];
  const float* U_f  =(const float*)d_in[11];
  const float* W_ff =(const float*)d_in[12];
  const float* W_sd =(const float*)d_in[13];
  const float* W_sd2=(const float*)d_in[14];
  const float* W_sf =(const float*)d_in[15];
  const float* ln_g =(const float*)d_in[16];
  const float* ln_b =(const float*)d_in[17];

  const int N=in_sizes[0]/768;   // 87360
  const int T=N/NPT;             // 64
  const int MINT=T*NINT;         // 21824

  float* out0=(float*)d_out;
  float* out1=out0+(size_t)N*4;
  float* cbuf=out1+(size_t)T*4;  // c output region (live c-state)

  char* p=(char*)d_ws;
  auto alloc=[&](size_t bytes){ char* r=p; p+=((bytes+255)&~(size_t)255); return r; };
  f16*   fx   =(f16*)  alloc((size_t)N*768*2);
  f16*   hs16 =(f16*)  alloc((size_t)16384*HD*2);
  float* csum =(float*)alloc((size_t)16384*HD*4);
  f16*   h16  =(f16*)  alloc((size_t)N*HD*2);
  f16*   WilL =(f16*)  alloc((size_t)1536*768*2);
  f16*   WilI =(f16*)  alloc((size_t)1536*1280*2);
  f16*   Wcat2=(f16*)  alloc((size_t)1536*1280*2);   // level-5 64-tile layout
  f16*   Wfc  =(f16*)  alloc((size_t)512*768*2);
  f16*   Ufc  =(f16*)  alloc((size_t)512*512*2);
  float* tmp4 =(float*)alloc((size_t)4*1024*4);
  float* Wy   =(float*)alloc((size_t)4*512*4);
  float* XWf  =(float*)alloc((size_t)MINT*512*4);

  // fused prep (all elementwise conversions + tmp4), then Wy
  {
    size_t nfeat8=(size_t)N*768/8;
    size_t tot=nfeat8+(size_t)1536*768+(size_t)1536*1280*2+(size_t)512*768/8+(size_t)512*512/8+4096;
    int nb=(int)((tot+255)/256);
    k_prep<<<nb,256,0,stream>>>(features,W_iou,U_iou,W_f,U_f,W_sf,W_sd2,
                                fx,WilL,WilI,Wcat2,Wfc,Ufc,tmp4,nfeat8);
  }
  { k_wy2<<<8,256,0,stream>>>(W_sf,tmp4,W_sd,Wy); }

  static const int starts[6]={0,1024,1280,1344,1360,1364};
  static const int csh[6]  ={10,8,6,4,2,0};
  static const int counts[6]={1024,256,64,16,4,1};
  static const int xwoffs[6]={0,0,256,320,336,340};

  // fused leaf iou (2 M-tiles/block) + XWf
  {
    int nbLeaf=8*((T*1024)/256);             // 2048
    int nbXwf=4*((MINT+127)/128);            // 684
    k_leafxwf<<<nbLeaf+nbXwf,256,IOU_LDS,stream>>>(fx,WilL,b_iou,h16,cbuf,Wfc,XWf,nbLeaf,MINT);
  }

  for(int n=1;n<6;++n){
    int P=T*counts[n], E=T*counts[n-1];
    { int nb=4*(E/128);
      k_uh128p<<<nb,256,G128_LDS,stream>>>(h16,Ufc,b_f,XWf,cbuf,csum,hs16,
                                           starts[n-1],csh[n-1],xwoffs[n]); }
    if(P>=256){
      int nb=8*(P/256);
      k_iou128p<<<nb,256,IOU_LDS,stream>>>(fx,hs16,WilI,b_iou,csum,h16,cbuf,starts[n],csh[n]);
    }else{
      dim3 g(P/64,8);
      k_iou<<<g,256,0,stream>>>(fx,hs16,Wcat2,b_iou,csum,h16,cbuf,starts[n],csh[n],1280,1280);
    }
  }

  // heads (stance folded into Wy; root appended to final2 launch)
  {
    int nbMain=(N*64+255)/256;
    k_final2<<<nbMain+16,256,0,stream>>>(h16,Wy,ln_g,ln_b,out0,W_ff,out1,N,nbMain);
  }
}

// Round 25
// 736.852 us; speedup vs baseline: 1.2554x; 1.2554x over previous
//
#include <hip/hip_runtime.h>
#include <hip/hip_bf16.h>
#include <math.h>

typedef _Float16 f16;
typedef f16 f16x8 __attribute__((ext_vector_type(8)));
typedef float f32x4 __attribute__((ext_vector_type(4)));

#define NPT 1365
#define HD 512
#define NINT 341   // internal nodes per tree (256+64+16+4+1)
#define IOU_LDS (2*128*64*2 + 2*192*64*2)   // 81920 B -> 2 blocks/CU
#define G128_LDS (2*128*64*2 + 2*128*64*2)  // 65536 B -> 2 blocks/CU

__device__ __forceinline__ float frcp(float x){ return __builtin_amdgcn_rcpf(x); }
__device__ __forceinline__ float sigm(float x){ return frcp(1.0f+__expf(-x)); }
__device__ __forceinline__ float ftanh(float x){
  float e=__expf(2.f*fabsf(x));
  float t=1.f-2.f*frcp(e+1.f);
  return copysignf(t,x);
}

__device__ __forceinline__ void gll16(const void* g, void* l){
  __builtin_amdgcn_global_load_lds((const __attribute__((address_space(1))) void*)g,
                                   (__attribute__((address_space(3))) void*)l, 16, 0, 0);
}

// XCD-chunked bijection: phys%8 = XCD; each XCD gets a contiguous y-range with all x.
__device__ __forceinline__ void xcd_map(int phys, int nb, int xdim, int& x, int& my){
  int ytiles = nb / xdim;
  if((ytiles & 7)==0){
    int k = phys & 7, i = phys >> 3;
    my = k * (ytiles >> 3) + i / xdim;
    x  = i % xdim;
  }else{
    x  = phys % xdim;
    my = phys / xdim;
  }
}

// ================= fused prep: all elementwise weight/feature conversions =================
// seg0: features->fx (n8 threads, 8 elems each)
// seg1: WilL (leaf gate-interleaved, K=768)
// seg2: WilI (internal gate-interleaved, K=1280)
// seg3: Wcat2 (gate-major K=1280, level-5)
// seg4: W_f->Wfc (8 elems)
// seg5: U_f->Ufc (8 elems)
// seg6: tmp4[j][e] = Wsf[j]·W_sd2[:,e]
__global__ void k_prep(const float* __restrict__ features,
                       const float* __restrict__ W_iou, const float* __restrict__ U_iou,
                       const float* __restrict__ W_f, const float* __restrict__ U_f,
                       const float* __restrict__ Wsf, const float* __restrict__ Wsd2,
                       f16* __restrict__ fx, f16* __restrict__ WilL, f16* __restrict__ WilI,
                       f16* __restrict__ Wcat2, f16* __restrict__ Wfc, f16* __restrict__ Ufc,
                       float* __restrict__ tmp4, size_t nfeat8)
{
  size_t gid=(size_t)blockIdx.x*256+threadIdx.x;
  const size_t n0=nfeat8;
  const size_t n1=n0+(size_t)1536*768;
  const size_t n2=n1+(size_t)1536*1280;
  const size_t n3=n2+(size_t)1536*1280;
  const size_t n4=n3+(size_t)512*768/8;
  const size_t n5=n4+(size_t)512*512/8;
  const size_t n6=n5+4096;
  if(gid<n0){
    size_t i=gid;
    const float4* sp=(const float4*)(features+i*8);
    float4 a=sp[0], b=sp[1];
    float v[8]={a.x,a.y,a.z,a.w,b.x,b.y,b.z,b.w};
    f16x8 h;
    #pragma unroll
    for(int e=0;e<8;++e) h[e]=(f16)v[e];
    *(f16x8*)(fx+i*8)=h;
  }else if(gid<n1){
    size_t i=gid-n0;
    int rp=(int)(i/768); int k=(int)(i-(size_t)rp*768);
    int f=rp>>4, rr=rp&15;
    int orig=(f%3)*512+(f/3)*16+rr;
    WilL[i]=(f16)W_iou[(size_t)orig*768+k];
  }else if(gid<n2){
    size_t i=gid-n1;
    int rp=(int)(i/1280); int k=(int)(i-(size_t)rp*1280);
    int f=rp>>4, rr=rp&15;
    int orig=(f%3)*512+(f/3)*16+rr;
    float v=(k<768)? W_iou[(size_t)orig*768+k] : U_iou[(size_t)orig*512+(k-768)];
    WilI[i]=(f16)v;
  }else if(gid<n3){
    size_t i=gid-n2;
    int r=(int)(i/1280); int k=(int)(i-(size_t)r*1280);
    float v=(k<768)? W_iou[(size_t)r*768+k] : U_iou[(size_t)r*512+(k-768)];
    Wcat2[i]=(f16)v;
  }else if(gid<n4){
    size_t i=gid-n3;
    const float4* sp=(const float4*)(W_f+i*8);
    float4 a=sp[0], b=sp[1];
    float v[8]={a.x,a.y,a.z,a.w,b.x,b.y,b.z,b.w};
    f16x8 h;
    #pragma unroll
    for(int e=0;e<8;++e) h[e]=(f16)v[e];
    *(f16x8*)(Wfc+i*8)=h;
  }else if(gid<n5){
    size_t i=gid-n4;
    const float4* sp=(const float4*)(U_f+i*8);
    float4 a=sp[0], b=sp[1];
    float v[8]={a.x,a.y,a.z,a.w,b.x,b.y,b.z,b.w};
    f16x8 h;
    #pragma unroll
    for(int e=0;e<8;++e) h[e]=(f16)v[e];
    *(f16x8*)(Ufc+i*8)=h;
  }else if(gid<n6){
    int idx=(int)(gid-n5);
    int j=idx>>10, e=idx&1023;
    float s=0.f;
    #pragma unroll 8
    for(int d=0;d<512;++d) s+=Wsf[j*512+d]*Wsd2[(size_t)d*1024+e];
    tmp4[(size_t)j*1024+e]=s;
  }
}

// ---------------- Wy[j][c] = Wsf[j][c] + sum_e tmp[j][e] * W_sd[e][c]  (4 x 512) ----------------
__global__ void k_wy2(const float* __restrict__ Wsf, const float* __restrict__ tmp,
                      const float* __restrict__ Wsd, float* __restrict__ Wy){
  int idx=blockIdx.x*256+threadIdx.x;
  if(idx>=2048) return;
  int j=idx>>9, c=idx&511;
  float s=Wsf[j*512+c];
  #pragma unroll 8
  for(int e=0;e<1024;++e) s+=tmp[j*1024+e]*Wsd[(size_t)e*512+c];
  Wy[(size_t)j*512+c]=s;
}

// ================= fused leaf iou + XWf (independent fx-consumers, one launch) =================
__global__ __launch_bounds__(256,2)
void k_leafxwf(const f16* __restrict__ fx, const f16* __restrict__ WilL,
               const float* __restrict__ bias, f16* __restrict__ h16,
               float* __restrict__ cbuf,
               const f16* __restrict__ Wfc, float* __restrict__ XWf,
               int nbLeaf, int Mtot)
{
  extern __shared__ char sm[];
  const int tid=threadIdx.x;
  const int w=tid>>6, lane=tid&63;
  const int lr=lane&15, lg=lane>>4;
  const unsigned swz=8u*((unsigned)(lane&7)^(unsigned)(lane>>3));

  if((int)blockIdx.x < nbLeaf){
    // ---------- leaf iou: 128 x 192, K=768, NT=12 ----------
    char* Abase=sm;
    char* Bbase=sm+32768;
    int x, my;
    xcd_map(blockIdx.x, nbLeaf, 8, x, my);
    const int m0=my*128;
    const int NT=12;

    unsigned fofs[4];
    #pragma unroll
    for(int i=0;i<4;++i){
      int r=w*32+i*8+(lane>>3);
      int m=m0+r;
      int t_=m>>10, j=m-(t_<<10);
      fofs[i]=(unsigned)(((size_t)t_*NPT+j)*768);
    }
    unsigned bofs[6];
    #pragma unroll
    for(int i=0;i<6;++i){
      int r=x*192+w*48+i*8+(lane>>3);
      bofs[i]=(unsigned)r*768u;
    }

    f32x4 acc[4][6];
    #pragma unroll
    for(int mi=0;mi<4;++mi)
      #pragma unroll
      for(int ni=0;ni<6;++ni) acc[mi][ni]=(f32x4){0.f,0.f,0.f,0.f};

    const int wr=(w>>1)*64;
    const int wcF=(w&1)*6;

    auto STAGE=[&](int buf, int t){
      const unsigned kofs=(unsigned)t*64u+swz;
      char* Ad=Abase+(size_t)buf*16384;
      #pragma unroll
      for(int i=0;i<4;++i)
        gll16(fx+fofs[i]+kofs, Ad+(w*32+i*8)*128);
      char* Bd=Bbase+(size_t)buf*24576;
      #pragma unroll
      for(int i=0;i<6;++i)
        gll16(WilL+bofs[i]+kofs, Bd+(w*48+i*8)*128);
    };

    auto COMPUTE=[&](int cur){
      const char* Ab=Abase+(size_t)cur*16384;
      const char* Bb=Bbase+(size_t)cur*24576;
      #pragma unroll
      for(int ks=0;ks<2;++ks){
        const unsigned cb=((unsigned)(ks*64+lg*16)) ^ ((unsigned)(lr&7)<<4);
        f16x8 av[4], bv[6];
        #pragma unroll
        for(int mi=0;mi<4;++mi)
          av[mi]=*(const f16x8*)(Ab+(unsigned)(wr+mi*16+lr)*128u+cb);
        #pragma unroll
        for(int ni=0;ni<6;++ni)
          bv[ni]=*(const f16x8*)(Bb+(unsigned)((wcF+ni)*16+lr)*128u+cb);
        __builtin_amdgcn_s_setprio(1);
        #pragma unroll
        for(int ni=0;ni<6;++ni)
          #pragma unroll
          for(int mi=0;mi<4;++mi)
            acc[mi][ni]=__builtin_amdgcn_mfma_f32_16x16x32_f16(av[mi],bv[ni],acc[mi][ni],0,0,0);
        __builtin_amdgcn_s_setprio(0);
      }
    };

    STAGE(0,0);
    STAGE(1,1);
    asm volatile("s_waitcnt vmcnt(10)" ::: "memory");
    __builtin_amdgcn_s_barrier();
    __builtin_amdgcn_sched_barrier(0);

    for(int t=0;t<NT;++t){
      COMPUTE(t&1);
      if(t+1<NT){
        __builtin_amdgcn_sched_barrier(0);
        __builtin_amdgcn_s_barrier();
        __builtin_amdgcn_sched_barrier(0);
        if(t+2<NT){
          STAGE(t&1, t+2);
          asm volatile("s_waitcnt vmcnt(10)" ::: "memory");
        }else{
          asm volatile("s_waitcnt vmcnt(0)" ::: "memory");
        }
        __builtin_amdgcn_s_barrier();
        __builtin_amdgcn_sched_barrier(0);
      }
    }

    #pragma unroll
    for(int mi=0;mi<4;++mi){
      #pragma unroll
      for(int cg=0;cg<2;++cg){
        const int col = x*64 + ((w&1)*2+cg)*16 + lr;
        const float bi=bias[col], bo=bias[col+512], bu=bias[col+1024];
        #pragma unroll
        for(int r=0;r<4;++r){
          const int mm=m0+wr+mi*16+lg*4+r;
          float iv=acc[mi][3*cg+0][r]+bi;
          float ov=acc[mi][3*cg+1][r]+bo;
          float uv=acc[mi][3*cg+2][r]+bu;
          float cn=sigm(iv)*ftanh(uv);
          float hn=sigm(ov)*ftanh(cn);
          const int tt=mm>>10, jj=mm-(tt<<10);
          const size_t nd=((size_t)tt*NPT+jj)*HD+col;
          cbuf[nd]=cn;
          h16[nd]=(f16)hn;
        }
      }
    }
  } else {
    // ---------- XWf: 128x128, K=768, NT=12 ----------
    char* Abase=sm;
    char* Bbase=sm+32768;
    int phys=(int)blockIdx.x-nbLeaf;
    int nb=(int)gridDim.x-nbLeaf;
    int xb, my;
    xcd_map(phys, nb, 4, xb, my);
    const int m0=my*128, n0=xb*128;
    const int NT=12;

    unsigned fofs[4];
    #pragma unroll
    for(int i=0;i<4;++i){
      int r=w*32+i*8+(lane>>3);
      int m=m0+r; if(m>=Mtot) m=Mtot-1;
      int t=m/NINT; int j=1024+(m-t*NINT);
      fofs[i]=(unsigned)(((size_t)t*NPT+j)*768);
    }
    unsigned bofs[4];
    #pragma unroll
    for(int i=0;i<4;++i){
      int r=n0+w*32+i*8+(lane>>3);
      bofs[i]=(unsigned)r*768u;
    }

    f32x4 acc[4][4];
    #pragma unroll
    for(int mi=0;mi<4;++mi)
      #pragma unroll
      for(int ni=0;ni<4;++ni) acc[mi][ni]=(f32x4){0.f,0.f,0.f,0.f};

    const int wr=(w>>1)*64, wc=(w&1)*64;

    auto STAGE=[&](int buf, int t){
      const unsigned ak=(unsigned)t*64u+swz;
      char* Ad=Abase+(size_t)buf*16384;
      #pragma unroll
      for(int i=0;i<4;++i)
        gll16(fx+fofs[i]+ak, Ad+(w*32+i*8)*128);
      char* Bd=Bbase+(size_t)buf*16384;
      #pragma unroll
      for(int i=0;i<4;++i)
        gll16(Wfc+bofs[i]+ak, Bd+(w*32+i*8)*128);
    };

    auto COMPUTE=[&](int cur){
      const char* Ab=Abase+(size_t)cur*16384;
      const char* Bb=Bbase+(size_t)cur*16384;
      #pragma unroll
      for(int ks=0;ks<2;++ks){
        const unsigned cb=((unsigned)(ks*64+lg*16)) ^ ((unsigned)(lr&7)<<4);
        f16x8 av[4], bv[4];
        #pragma unroll
        for(int mi=0;mi<4;++mi)
          av[mi]=*(const f16x8*)(Ab+(unsigned)(wr+mi*16+lr)*128u+cb);
        #pragma unroll
        for(int ni=0;ni<4;++ni)
          bv[ni]=*(const f16x8*)(Bb+(unsigned)((wc+ni*16)+lr)*128u+cb);
        __builtin_amdgcn_s_setprio(1);
        #pragma unroll
        for(int ni=0;ni<4;++ni)
          #pragma unroll
          for(int mi=0;mi<4;++mi)
            acc[mi][ni]=__builtin_amdgcn_mfma_f32_16x16x32_f16(av[mi],bv[ni],acc[mi][ni],0,0,0);
        __builtin_amdgcn_s_setprio(0);
      }
    };

    STAGE(0,0);
    STAGE(1,1);
    asm volatile("s_waitcnt vmcnt(8)" ::: "memory");
    __builtin_amdgcn_s_barrier();
    __builtin_amdgcn_sched_barrier(0);

    for(int t=0;t<NT;++t){
      COMPUTE(t&1);
      if(t+1<NT){
        __builtin_amdgcn_sched_barrier(0);
        __builtin_amdgcn_s_barrier();
        __builtin_amdgcn_sched_barrier(0);
        if(t+2<NT){
          STAGE(t&1, t+2);
          asm volatile("s_waitcnt vmcnt(8)" ::: "memory");
        }else{
          asm volatile("s_waitcnt vmcnt(0)" ::: "memory");
        }
        __builtin_amdgcn_s_barrier();
        __builtin_amdgcn_sched_barrier(0);
      }
    }

    #pragma unroll
    for(int mi=0;mi<4;++mi){
      #pragma unroll
      for(int ni=0;ni<4;++ni){
        const int col=n0+wc+ni*16+lr;
        #pragma unroll
        for(int r=0;r<4;++r){
          const int mm=m0+wr+mi*16+lg*4+r;
          if(mm<Mtot) XWf[(size_t)mm*512+col]=acc[mi][ni][r];
        }
      }
    }
  }
}

// ================= internal iou GEMM: 128 x 192, f16, XCD-chunked =================
__global__ __launch_bounds__(256,2)
void k_iou128p(const f16* __restrict__ fx, const f16* __restrict__ hs16,
               const f16* __restrict__ Wil, const float* __restrict__ bias,
               const float* __restrict__ csum, f16* __restrict__ h16,
               float* __restrict__ cbuf,
               int start_n, int shift)
{
  extern __shared__ char sm[];                 // A: 2x16384, B: 2x24576
  char* Abase=sm;
  char* Bbase=sm+32768;
  const int tid=threadIdx.x;
  const int w=tid>>6, lane=tid&63;
  int x, my;
  xcd_map(blockIdx.x, gridDim.x, 8, x, my);
  const int m0=my*128;
  const int K=1280;
  const int NT=20;

  unsigned fofs[4], hofs[4];
  #pragma unroll
  for(int i=0;i<4;++i){
    int r=w*32+i*8+(lane>>3);
    int m=m0+r;
    int t_=m>>shift, j=m-(t_<<shift);
    fofs[i]=(unsigned)(((size_t)t_*NPT+start_n+j)*768);
    hofs[i]=(unsigned)m*512u;
  }
  unsigned bofs[6];
  #pragma unroll
  for(int i=0;i<6;++i){
    int r=x*192+w*48+i*8+(lane>>3);
    bofs[i]=(unsigned)r*(unsigned)K;
  }
  const unsigned swz=8u*((unsigned)(lane&7)^(unsigned)(lane>>3));

  f32x4 acc[4][6];
  #pragma unroll
  for(int mi=0;mi<4;++mi)
    #pragma unroll
    for(int ni=0;ni<6;++ni) acc[mi][ni]=(f32x4){0.f,0.f,0.f,0.f};

  const int wr=(w>>1)*64;
  const int wcF=(w&1)*6;
  const int lr=lane&15, lg=lane>>4;

  auto STAGE=[&](int buf, int t){
    const f16* base; int kt; bool useF;
    if(t<12){ base=fx;   kt=t;    useF=true;  }
    else    { base=hs16; kt=t-12; useF=false; }
    const unsigned kofs=(unsigned)kt*64u+swz;
    char* Ad=Abase+(size_t)buf*16384;
    #pragma unroll
    for(int i=0;i<4;++i){
      const f16* g=base+(useF?fofs[i]:hofs[i])+kofs;
      gll16(g, Ad+(w*32+i*8)*128);
    }
    const unsigned bk=(unsigned)t*64u+swz;
    char* Bd=Bbase+(size_t)buf*24576;
    #pragma unroll
    for(int i=0;i<6;++i){
      gll16(Wil+bofs[i]+bk, Bd+(w*48+i*8)*128);
    }
  };

  auto COMPUTE=[&](int cur){
    const char* Ab=Abase+(size_t)cur*16384;
    const char* Bb=Bbase+(size_t)cur*24576;
    #pragma unroll
    for(int ks=0;ks<2;++ks){
      const unsigned cb=((unsigned)(ks*64+lg*16)) ^ ((unsigned)(lr&7)<<4);
      f16x8 av[4], bv[6];
      #pragma unroll
      for(int mi=0;mi<4;++mi)
        av[mi]=*(const f16x8*)(Ab+(unsigned)(wr+mi*16+lr)*128u+cb);
      #pragma unroll
      for(int ni=0;ni<6;++ni)
        bv[ni]=*(const f16x8*)(Bb+(unsigned)((wcF+ni)*16+lr)*128u+cb);
      __builtin_amdgcn_s_setprio(1);
      #pragma unroll
      for(int ni=0;ni<6;++ni)
        #pragma unroll
        for(int mi=0;mi<4;++mi)
          acc[mi][ni]=__builtin_amdgcn_mfma_f32_16x16x32_f16(av[mi],bv[ni],acc[mi][ni],0,0,0);
      __builtin_amdgcn_s_setprio(0);
    }
  };

  STAGE(0,0);
  STAGE(1,1);
  asm volatile("s_waitcnt vmcnt(10)" ::: "memory");
  __builtin_amdgcn_s_barrier();
  __builtin_amdgcn_sched_barrier(0);

  for(int t=0;t<NT;++t){
    COMPUTE(t&1);
    if(t+1<NT){
      __builtin_amdgcn_sched_barrier(0);
      __builtin_amdgcn_s_barrier();
      __builtin_amdgcn_sched_barrier(0);
      if(t+2<NT){
        STAGE(t&1, t+2);
        asm volatile("s_waitcnt vmcnt(10)" ::: "memory");
      }else{
        asm volatile("s_waitcnt vmcnt(0)" ::: "memory");
      }
      __builtin_amdgcn_s_barrier();
      __builtin_amdgcn_sched_barrier(0);
    }
  }

  #pragma unroll
  for(int mi=0;mi<4;++mi){
    #pragma unroll
    for(int cg=0;cg<2;++cg){
      const int col = x*64 + ((w&1)*2+cg)*16 + lr;
      const float bi=bias[col], bo=bias[col+512], bu=bias[col+1024];
      #pragma unroll
      for(int r=0;r<4;++r){
        const int mm=m0+wr+mi*16+lg*4+r;
        float iv=acc[mi][3*cg+0][r]+bi;
        float ov=acc[mi][3*cg+1][r]+bo;
        float uv=acc[mi][3*cg+2][r]+bu;
        float cn=sigm(iv)*ftanh(uv);
        cn+=csum[(size_t)mm*HD+col];
        float hn=sigm(ov)*ftanh(cn);
        const int tt=mm>>shift, jj=mm-(tt<<shift);
        const size_t nd=((size_t)tt*NPT+start_n+jj)*HD+col;
        cbuf[nd]=cn;
        h16[nd]=(f16)hn;
      }
    }
  }
}

// ---------------- old 64-tile iou (level 5 only, P=64; K=1280 gate-major layout, f16) ----------------
__global__ __launch_bounds__(256)
void k_iou(const f16* __restrict__ fx, const f16* __restrict__ hs16,
           const f16* __restrict__ Wcat, const float* __restrict__ bias,
           const float* __restrict__ csum, f16* __restrict__ h16,
           float* __restrict__ cbuf,
           int start_n, int shift, int K, int KB)
{
  __shared__ f16 As[64][40];
  __shared__ f16 Bs[3][64][40];
  const int tid=threadIdx.x;
  const int m0=blockIdx.x*64, n0=blockIdx.y*64;
  const int srow=tid>>2, skc=(tid&3)*8;
  const int m=m0+srow;
  const int t=m>>shift, j=m-(t<<shift);
  const size_t frow=((size_t)t*NPT+start_n+j)*768;
  const f16* aF=fx+frow;
  const f16* aH=hs16+(size_t)m*HD;
  const f16* bp0=Wcat+(size_t)(n0+srow)*KB;
  const f16* bp1=Wcat+(size_t)(512+n0+srow)*KB;
  const f16* bp2=Wcat+(size_t)(1024+n0+srow)*KB;

  f32x4 acc[3][2][2];
  #pragma unroll
  for(int g=0;g<3;++g)
    #pragma unroll
    for(int mi=0;mi<2;++mi)
      #pragma unroll
      for(int ni=0;ni<2;++ni) acc[g][mi][ni]=(f32x4){0.f,0.f,0.f,0.f};

  const int w=tid>>6, lane=tid&63;
  const int wr=(w>>1)*32, wc=(w&1)*32;
  const int lr=lane&15, lg=lane>>4;

  for(int k0=0;k0<K;k0+=32){
    const f16* ap = (k0<768)? (aF+k0) : (aH+(k0-768));
    *(f16x8*)&As[srow][skc]=*(const f16x8*)(ap+skc);
    *(f16x8*)&Bs[0][srow][skc]=*(const f16x8*)(bp0+k0+skc);
    *(f16x8*)&Bs[1][srow][skc]=*(const f16x8*)(bp1+k0+skc);
    *(f16x8*)&Bs[2][srow][skc]=*(const f16x8*)(bp2+k0+skc);
    __syncthreads();
    f16x8 a0=*(f16x8*)&As[wr+lr][lg*8];
    f16x8 a1=*(f16x8*)&As[wr+16+lr][lg*8];
    #pragma unroll
    for(int g=0;g<3;++g){
      #pragma unroll
      for(int ni=0;ni<2;++ni){
        f16x8 bv=*(f16x8*)&Bs[g][wc+ni*16+lr][lg*8];
        acc[g][0][ni]=__builtin_amdgcn_mfma_f32_16x16x32_f16(a0,bv,acc[g][0][ni],0,0,0);
        acc[g][1][ni]=__builtin_amdgcn_mfma_f32_16x16x32_f16(a1,bv,acc[g][1][ni],0,0,0);
      }
    }
    __syncthreads();
  }

  #pragma unroll
  for(int mi=0;mi<2;++mi){
    #pragma unroll
    for(int ni=0;ni<2;++ni){
      const int col=n0+wc+ni*16+lr;
      const float bi=bias[col], bo=bias[col+512], bu=bias[col+1024];
      #pragma unroll
      for(int r=0;r<4;++r){
        const int mm=m0+wr+mi*16+lg*4+r;
        float iv=acc[0][mi][ni][r]+bi;
        float ov=acc[1][mi][ni][r]+bo;
        float uv=acc[2][mi][ni][r]+bu;
        float cn=sigm(iv)*ftanh(uv);
        cn+=csum[(size_t)mm*HD+col];
        float hn=sigm(ov)*ftanh(cn);
        const int tt=mm>>shift, jj=mm-(tt<<shift);
        const size_t nd=((size_t)tt*NPT+start_n+jj)*HD+col;
        cbuf[nd]=cn;
        h16[nd]=(f16)hn;
      }
    }
  }
}

// ================= Uh forget-gate: pipelined 128x128 (NT=8, f16) + fused csum/hsum =================
__global__ __launch_bounds__(256,2)
void k_uh128p(const f16* __restrict__ h16,
              const f16* __restrict__ Ufc, const float* __restrict__ bias,
              const float* __restrict__ XWf, const float* __restrict__ cbuf,
              float* __restrict__ csum, f16* __restrict__ hs16,
              int start_ch, int lc, int xwoff)
{
  extern __shared__ char sm[];     // A: 2x16384, B: 2x16384
  char* Abase=sm;
  char* Bbase=sm+32768;
  const int tid=threadIdx.x;
  const int w=tid>>6, lane=tid&63;
  int xb, my;
  xcd_map(blockIdx.x, gridDim.x, 4, xb, my);
  const int e0=my*128, n0=xb*128;
  const int NT=8;

  unsigned hofs[4];
  #pragma unroll
  for(int i=0;i<4;++i){
    int r=w*32+i*8+(lane>>3);
    int e=e0+r;
    int t=e>>lc, ei=e-(t<<lc);
    hofs[i]=(unsigned)(((size_t)t*NPT+start_ch+ei)*HD);
  }
  unsigned bofs[4];
  #pragma unroll
  for(int i=0;i<4;++i){
    int r=n0+w*32+i*8+(lane>>3);
    bofs[i]=(unsigned)r*512u;
  }
  const unsigned swz=8u*((unsigned)(lane&7)^(unsigned)(lane>>3));

  f32x4 acc[4][4];
  #pragma unroll
  for(int mi=0;mi<4;++mi)
    #pragma unroll
    for(int ni=0;ni<4;++ni) acc[mi][ni]=(f32x4){0.f,0.f,0.f,0.f};

  const int wr=(w>>1)*64, wc=(w&1)*64;
  const int lr=lane&15, lg=lane>>4;

  auto STAGE=[&](int buf, int t){
    const unsigned ak=(unsigned)t*64u+swz;
    char* Ad=Abase+(size_t)buf*16384;
    #pragma unroll
    for(int i=0;i<4;++i)
      gll16(h16+hofs[i]+ak, Ad+(w*32+i*8)*128);
    char* Bd=Bbase+(size_t)buf*16384;
    #pragma unroll
    for(int i=0;i<4;++i)
      gll16(Ufc+bofs[i]+ak, Bd+(w*32+i*8)*128);
  };

  auto COMPUTE=[&](int cur){
    const char* Ab=Abase+(size_t)cur*16384;
    const char* Bb=Bbase+(size_t)cur*16384;
    #pragma unroll
    for(int ks=0;ks<2;++ks){
      const unsigned cb=((unsigned)(ks*64+lg*16)) ^ ((unsigned)(lr&7)<<4);
      f16x8 av[4], bv[4];
      #pragma unroll
      for(int mi=0;mi<4;++mi)
        av[mi]=*(const f16x8*)(Ab+(unsigned)(wr+mi*16+lr)*128u+cb);
      #pragma unroll
      for(int ni=0;ni<4;++ni)
        bv[ni]=*(const f16x8*)(Bb+(unsigned)((wc+ni*16)+lr)*128u+cb);
      __builtin_amdgcn_s_setprio(1);
      #pragma unroll
      for(int ni=0;ni<4;++ni)
        #pragma unroll
        for(int mi=0;mi<4;++mi)
          acc[mi][ni]=__builtin_amdgcn_mfma_f32_16x16x32_f16(av[mi],bv[ni],acc[mi][ni],0,0,0);
      __builtin_amdgcn_s_setprio(0);
    }
  };

  STAGE(0,0);
  STAGE(1,1);
  asm volatile("s_waitcnt vmcnt(8)" ::: "memory");
  __builtin_amdgcn_s_barrier();
  __builtin_amdgcn_sched_barrier(0);

  for(int t=0;t<NT;++t){
    COMPUTE(t&1);
    if(t+1<NT){
      __builtin_amdgcn_sched_barrier(0);
      __builtin_amdgcn_s_barrier();
      __builtin_amdgcn_sched_barrier(0);
      if(t+2<NT){
        STAGE(t&1, t+2);
        asm volatile("s_waitcnt vmcnt(8)" ::: "memory");
      }else{
        asm volatile("s_waitcnt vmcnt(0)" ::: "memory");
      }
      __builtin_amdgcn_s_barrier();
      __builtin_amdgcn_sched_barrier(0);
    }
  }

  #pragma unroll
  for(int mi=0;mi<4;++mi){
    const int ebase=e0+wr+mi*16+lg*4;
    const int tt=ebase>>lc, eib=ebase-(tt<<lc);
    const int inode=tt*NINT + xwoff + (eib>>2);
    const int par=ebase>>2;
    #pragma unroll
    for(int ni=0;ni<4;++ni){
      const int col=n0+wc+ni*16+lr;
      const float base=bias[col]+XWf[(size_t)inode*512+col];
      const size_t chbase=((size_t)tt*NPT+start_ch+eib)*HD+col;
      float s=0.f, hsv=0.f;
      #pragma unroll
      for(int r=0;r<4;++r){
        const size_t ci=chbase+(size_t)r*HD;
        float fv=sigm(acc[mi][ni][r]+base);
        s+=fv*cbuf[ci];
        hsv+=(float)h16[ci];
      }
      csum[(size_t)par*HD+col]=s;
      hs16[(size_t)par*HD+col]=(f16)hsv;
    }
  }
}

// ---------------- final heads: h_st softmax (+root blocks appended) ----------------
__global__ __launch_bounds__(256)
void k_final2(const f16* __restrict__ h16,
              const float* __restrict__ Wy, const float* __restrict__ gamma,
              const float* __restrict__ beta, float* __restrict__ out0,
              const float* __restrict__ Wff, float* __restrict__ out1,
              int Nn, int nbMain)
{
  const int tid=threadIdx.x;
  if((int)blockIdx.x < nbMain){
    const int gtid=blockIdx.x*256+tid;
    const int node=gtid>>6, lane=gtid&63;
    if(node>=Nn) return;
    const size_t base=(size_t)node*HD+lane*8;
    f16x8 hv=*(const f16x8*)(h16+base);
    float hf[8];
    #pragma unroll
    for(int e=0;e<8;++e) hf[e]=(float)hv[e];
    float y[4];
    #pragma unroll
    for(int jj=0;jj<4;++jj){
      const float* wp=Wy+jj*HD+lane*8;
      float s=0.f;
      #pragma unroll
      for(int e=0;e<8;++e) s+=hf[e]*wp[e];
      #pragma unroll
      for(int off=32;off>=1;off>>=1) s+=__shfl_xor(s,off,64);
      y[jj]=s;
    }
    if(lane==0){
      float mu=0.25f*(y[0]+y[1]+y[2]+y[3]);
      float var=0.f;
      #pragma unroll
      for(int jj=0;jj<4;++jj){ float d=y[jj]-mu; var+=d*d; }
      var*=0.25f;
      float rs=rsqrtf(var+1e-6f);
      float z[4], zmax=-1e30f;
      #pragma unroll
      for(int jj=0;jj<4;++jj){ z[jj]=(y[jj]-mu)*rs*gamma[jj]+beta[jj]; zmax=fmaxf(zmax,z[jj]); }
      float es=0.f;
      #pragma unroll
      for(int jj=0;jj<4;++jj){ z[jj]=__expf(z[jj]-zmax); es+=z[jj]; }
      float inv=frcp(es);
      #pragma unroll
      for(int jj=0;jj<4;++jj) out0[(size_t)node*4+jj]=z[jj]*inv;
    }
  } else {
    const int gtid=((int)blockIdx.x-nbMain)*256+tid;
    const int tt=gtid>>6, lane=gtid&63;
    if(tt>=64) return;
    const size_t base=((size_t)tt*NPT+1364)*HD+lane*8;
    f16x8 hv=*(const f16x8*)(h16+base);
    float hf[8];
    #pragma unroll
    for(int e=0;e<8;++e) hf[e]=(float)hv[e];
    float y[4];
    #pragma unroll
    for(int jj=0;jj<4;++jj){
      const float* wp=Wff+jj*HD+lane*8;
      float s=0.f;
      #pragma unroll
      for(int e=0;e<8;++e) s+=hf[e]*wp[e];
      #pragma unroll
      for(int off=32;off>=1;off>>=1) s+=__shfl_xor(s,off,64);
      y[jj]=s;
    }
    if(lane==0){
      float zmax=fmaxf(fmaxf(y[0],y[1]),fmaxf(y[2],y[3]));
      float es=0.f, z[4];
      #pragma unroll
      for(int jj=0;jj<4;++jj){ z[jj]=__expf(y[jj]-zmax); es+=z[jj]; }
      float inv=frcp(es);
      #pragma unroll
      for(int jj=0;jj<4;++jj) out1[(size_t)tt*4+jj]=z[jj]*inv;
    }
  }
}

extern "C" void kernel_launch(void* const* d_in, const int* in_sizes, int n_in,
                              void* d_out, int out_size, void* d_ws, size_t ws_size,
                              hipStream_t stream)
{
  const float* features=(const float*)d_in[0];
  const float* W_iou=(const float*)d_in[6];
  const float* b_iou=(const float*)d_in[7];
  const float* U_iou=(const float*)d_in[8];
  const float* W_f  =(const float*)d_in[9];
  const float* b_f  =(const float*)d_in[10];
  const float* U_f  =(const float*)d_in[11];
  const float* W_ff =(const float*)d_in[12];
  const float* W_sd =(const float*)d_in[13];
  const float* W_sd2=(const float*)d_in[14];
  const float* W_sf =(const float*)d_in[15];
  const float* ln_g =(const float*)d_in[16];
  const float* ln_b =(const float*)d_in[17];

  const int N=in_sizes[0]/768;   // 87360
  const int T=N/NPT;             // 64
  const int MINT=T*NINT;         // 21824

  float* out0=(float*)d_out;
  float* out1=out0+(size_t)N*4;
  float* cbuf=out1+(size_t)T*4;  // c output region (live c-state)

  char* p=(char*)d_ws;
  auto alloc=[&](size_t bytes){ char* r=p; p+=((bytes+255)&~(size_t)255); return r; };
  f16*   fx   =(f16*)  alloc((size_t)N*768*2);
  f16*   hs16 =(f16*)  alloc((size_t)16384*HD*2);
  float* csum =(float*)alloc((size_t)16384*HD*4);
  f16*   h16  =(f16*)  alloc((size_t)N*HD*2);
  f16*   WilL =(f16*)  alloc((size_t)1536*768*2);
  f16*   WilI =(f16*)  alloc((size_t)1536*1280*2);
  f16*   Wcat2=(f16*)  alloc((size_t)1536*1280*2);   // level-5 64-tile layout
  f16*   Wfc  =(f16*)  alloc((size_t)512*768*2);
  f16*   Ufc  =(f16*)  alloc((size_t)512*512*2);
  float* tmp4 =(float*)alloc((size_t)4*1024*4);
  float* Wy   =(float*)alloc((size_t)4*512*4);
  float* XWf  =(float*)alloc((size_t)MINT*512*4);

  // fused prep (all elementwise conversions + tmp4), then Wy
  {
    size_t nfeat8=(size_t)N*768/8;
    size_t tot=nfeat8+(size_t)1536*768+(size_t)1536*1280*2+(size_t)512*768/8+(size_t)512*512/8+4096;
    int nb=(int)((tot+255)/256);
    k_prep<<<nb,256,0,stream>>>(features,W_iou,U_iou,W_f,U_f,W_sf,W_sd2,
                                fx,WilL,WilI,Wcat2,Wfc,Ufc,tmp4,nfeat8);
  }
  { k_wy2<<<8,256,0,stream>>>(W_sf,tmp4,W_sd,Wy); }

  static const int starts[6]={0,1024,1280,1344,1360,1364};
  static const int csh[6]  ={10,8,6,4,2,0};
  static const int counts[6]={1024,256,64,16,4,1};
  static const int xwoffs[6]={0,0,256,320,336,340};

  // fused leaf iou + XWf (independent, one launch)
  {
    int nbLeaf=8*((T*1024)/128);             // 4096
    int nbXwf=4*((MINT+127)/128);            // 684
    k_leafxwf<<<nbLeaf+nbXwf,256,IOU_LDS,stream>>>(fx,WilL,b_iou,h16,cbuf,Wfc,XWf,nbLeaf,MINT);
  }

  for(int n=1;n<6;++n){
    int P=T*counts[n], E=T*counts[n-1];
    { int nb=4*(E/128);
      k_uh128p<<<nb,256,G128_LDS,stream>>>(h16,Ufc,b_f,XWf,cbuf,csum,hs16,
                                           starts[n-1],csh[n-1],xwoffs[n]); }
    if(P>=128){
      int nb=8*(P/128);
      k_iou128p<<<nb,256,IOU_LDS,stream>>>(fx,hs16,WilI,b_iou,csum,h16,cbuf,starts[n],csh[n]);
    }else{
      dim3 g(P/64,8);
      k_iou<<<g,256,0,stream>>>(fx,hs16,Wcat2,b_iou,csum,h16,cbuf,starts[n],csh[n],1280,1280);
    }
  }

  // heads (stance folded into Wy; root appended to final2 launch)
  {
    int nbMain=(N*64+255)/256;
    k_final2<<<nbMain+16,256,0,stream>>>(h16,Wy,ln_g,ln_b,out0,W_ff,out1,N,nbMain);
  }
}

// Round 26
// 713.181 us; speedup vs baseline: 1.2971x; 1.0332x over previous
//
#include <hip/hip_runtime.h>
#include <hip/hip_bf16.h>
#include <math.h>

typedef _Float16 f16;
typedef f16 f16x8 __attribute__((ext_vector_type(8)));
typedef float f32x4 __attribute__((ext_vector_type(4)));

#define NPT 1365
#define HD 512
#define NINT 341   // internal nodes per tree (256+64+16+4+1)
#define IOU_LDS (2*128*64*2 + 2*192*64*2)   // 81920 B -> 2 blocks/CU
#define G128_LDS (2*128*64*2 + 2*128*64*2)  // 65536 B -> 2 blocks/CU

__device__ __forceinline__ float frcp(float x){ return __builtin_amdgcn_rcpf(x); }
__device__ __forceinline__ float sigm(float x){ return frcp(1.0f+__expf(-x)); }
__device__ __forceinline__ float ftanh(float x){
  float e=__expf(2.f*fabsf(x));
  float t=1.f-2.f*frcp(e+1.f);
  return copysignf(t,x);
}

__device__ __forceinline__ void gll16(const void* g, void* l){
  __builtin_amdgcn_global_load_lds((const __attribute__((address_space(1))) void*)g,
                                   (__attribute__((address_space(3))) void*)l, 16, 0, 0);
}

// XCD-chunked bijection: phys%8 = XCD; each XCD gets a contiguous y-range with all x.
__device__ __forceinline__ void xcd_map(int phys, int nb, int xdim, int& x, int& my){
  int ytiles = nb / xdim;
  if((ytiles & 7)==0){
    int k = phys & 7, i = phys >> 3;
    my = k * (ytiles >> 3) + i / xdim;
    x  = i % xdim;
  }else{
    x  = phys % xdim;
    my = phys / xdim;
  }
}

__device__ __forceinline__ f16x8 cvt8(const float* src){
  const float4* sp=(const float4*)src;
  float4 a=sp[0], b=sp[1];
  float v[8]={a.x,a.y,a.z,a.w,b.x,b.y,b.z,b.w};
  f16x8 h;
  #pragma unroll
  for(int e=0;e<8;++e) h[e]=(f16)v[e];
  return h;
}

// ================= fused prep: all elementwise weight/feature conversions (8-wide) =================
// seg0: features->fx            (nfeat8 threads, 8 elems each)
// seg1: WilL  (leaf gate-interleaved, K=768)   8 elems/thread
// seg2: WilI  (internal gate-interleaved, K=1280) 8 elems/thread
// seg3: Wcat2 (gate-major K=1280, level-5)     8 elems/thread
// seg4: W_f->Wfc  8 elems
// seg5: U_f->Ufc  8 elems
// seg6: tmp4[j][e] = Wsf[j]·W_sd2[:,e]
__global__ void k_prep(const float* __restrict__ features,
                       const float* __restrict__ W_iou, const float* __restrict__ U_iou,
                       const float* __restrict__ W_f, const float* __restrict__ U_f,
                       const float* __restrict__ Wsf, const float* __restrict__ Wsd2,
                       f16* __restrict__ fx, f16* __restrict__ WilL, f16* __restrict__ WilI,
                       f16* __restrict__ Wcat2, f16* __restrict__ Wfc, f16* __restrict__ Ufc,
                       float* __restrict__ tmp4, size_t nfeat8)
{
  size_t gid=(size_t)blockIdx.x*256+threadIdx.x;
  const size_t n0=nfeat8;
  const size_t n1=n0+(size_t)1536*768/8;     // WilL, 8-wide
  const size_t n2=n1+(size_t)1536*1280/8;    // WilI, 8-wide
  const size_t n3=n2+(size_t)1536*1280/8;    // Wcat2, 8-wide
  const size_t n4=n3+(size_t)512*768/8;
  const size_t n5=n4+(size_t)512*512/8;
  const size_t n6=n5+4096;
  if(gid<n0){
    size_t i=gid;
    *(f16x8*)(fx+i*8)=cvt8(features+i*8);
  }else if(gid<n1){
    size_t i8=gid-n0;
    int rp=(int)(i8/96); int k=(int)(i8-(size_t)rp*96)*8;
    int f=rp>>4, rr=rp&15;
    int orig=(f%3)*512+(f/3)*16+rr;
    *(f16x8*)(WilL+(size_t)rp*768+k)=cvt8(W_iou+(size_t)orig*768+k);
  }else if(gid<n2){
    size_t i8=gid-n1;
    int rp=(int)(i8/160); int k=(int)(i8-(size_t)rp*160)*8;
    int f=rp>>4, rr=rp&15;
    int orig=(f%3)*512+(f/3)*16+rr;
    const float* src=(k<768)? (W_iou+(size_t)orig*768+k) : (U_iou+(size_t)orig*512+(k-768));
    *(f16x8*)(WilI+(size_t)rp*1280+k)=cvt8(src);
  }else if(gid<n3){
    size_t i8=gid-n2;
    int r=(int)(i8/160); int k=(int)(i8-(size_t)r*160)*8;
    const float* src=(k<768)? (W_iou+(size_t)r*768+k) : (U_iou+(size_t)r*512+(k-768));
    *(f16x8*)(Wcat2+(size_t)r*1280+k)=cvt8(src);
  }else if(gid<n4){
    size_t i=gid-n3;
    *(f16x8*)(Wfc+i*8)=cvt8(W_f+i*8);
  }else if(gid<n5){
    size_t i=gid-n4;
    *(f16x8*)(Ufc+i*8)=cvt8(U_f+i*8);
  }else if(gid<n6){
    int idx=(int)(gid-n5);
    int j=idx>>10, e=idx&1023;
    float s=0.f;
    #pragma unroll 8
    for(int d=0;d<512;++d) s+=Wsf[j*512+d]*Wsd2[(size_t)d*1024+e];
    tmp4[(size_t)j*1024+e]=s;
  }
}

// ---------------- Wy[j][c] = Wsf[j][c] + sum_e tmp[j][e] * W_sd[e][c]  (4 x 512) ----------------
__global__ void k_wy2(const float* __restrict__ Wsf, const float* __restrict__ tmp,
                      const float* __restrict__ Wsd, float* __restrict__ Wy){
  int idx=blockIdx.x*256+threadIdx.x;
  if(idx>=2048) return;
  int j=idx>>9, c=idx&511;
  float s=Wsf[j*512+c];
  #pragma unroll 8
  for(int e=0;e<1024;++e) s+=tmp[j*1024+e]*Wsd[(size_t)e*512+c];
  Wy[(size_t)j*512+c]=s;
}

// ================= fused leaf iou + XWf (independent fx-consumers, one launch) =================
__global__ __launch_bounds__(256,2)
void k_leafxwf(const f16* __restrict__ fx, const f16* __restrict__ WilL,
               const float* __restrict__ bias, f16* __restrict__ h16,
               float* __restrict__ cbuf,
               const f16* __restrict__ Wfc, f16* __restrict__ XWf,
               int nbLeaf, int Mtot)
{
  extern __shared__ char sm[];
  const int tid=threadIdx.x;
  const int w=tid>>6, lane=tid&63;
  const int lr=lane&15, lg=lane>>4;
  const unsigned swz=8u*((unsigned)(lane&7)^(unsigned)(lane>>3));

  if((int)blockIdx.x < nbLeaf){
    // ---------- leaf iou: 128 x 192, K=768, NT=12 ----------
    char* Abase=sm;
    char* Bbase=sm+32768;
    int x, my;
    xcd_map(blockIdx.x, nbLeaf, 8, x, my);
    const int m0=my*128;
    const int NT=12;

    unsigned fofs[4];
    #pragma unroll
    for(int i=0;i<4;++i){
      int r=w*32+i*8+(lane>>3);
      int m=m0+r;
      int t_=m>>10, j=m-(t_<<10);
      fofs[i]=(unsigned)(((size_t)t_*NPT+j)*768);
    }
    unsigned bofs[6];
    #pragma unroll
    for(int i=0;i<6;++i){
      int r=x*192+w*48+i*8+(lane>>3);
      bofs[i]=(unsigned)r*768u;
    }

    f32x4 acc[4][6];
    #pragma unroll
    for(int mi=0;mi<4;++mi)
      #pragma unroll
      for(int ni=0;ni<6;++ni) acc[mi][ni]=(f32x4){0.f,0.f,0.f,0.f};

    const int wr=(w>>1)*64;
    const int wcF=(w&1)*6;

    auto STAGE=[&](int buf, int t){
      const unsigned kofs=(unsigned)t*64u+swz;
      char* Ad=Abase+(size_t)buf*16384;
      #pragma unroll
      for(int i=0;i<4;++i)
        gll16(fx+fofs[i]+kofs, Ad+(w*32+i*8)*128);
      char* Bd=Bbase+(size_t)buf*24576;
      #pragma unroll
      for(int i=0;i<6;++i)
        gll16(WilL+bofs[i]+kofs, Bd+(w*48+i*8)*128);
    };

    auto COMPUTE=[&](int cur){
      const char* Ab=Abase+(size_t)cur*16384;
      const char* Bb=Bbase+(size_t)cur*24576;
      #pragma unroll
      for(int ks=0;ks<2;++ks){
        const unsigned cb=((unsigned)(ks*64+lg*16)) ^ ((unsigned)(lr&7)<<4);
        f16x8 av[4], bv[6];
        #pragma unroll
        for(int mi=0;mi<4;++mi)
          av[mi]=*(const f16x8*)(Ab+(unsigned)(wr+mi*16+lr)*128u+cb);
        #pragma unroll
        for(int ni=0;ni<6;++ni)
          bv[ni]=*(const f16x8*)(Bb+(unsigned)((wcF+ni)*16+lr)*128u+cb);
        __builtin_amdgcn_s_setprio(1);
        #pragma unroll
        for(int ni=0;ni<6;++ni)
          #pragma unroll
          for(int mi=0;mi<4;++mi)
            acc[mi][ni]=__builtin_amdgcn_mfma_f32_16x16x32_f16(av[mi],bv[ni],acc[mi][ni],0,0,0);
        __builtin_amdgcn_s_setprio(0);
      }
    };

    STAGE(0,0);
    STAGE(1,1);
    asm volatile("s_waitcnt vmcnt(10)" ::: "memory");
    __builtin_amdgcn_s_barrier();
    __builtin_amdgcn_sched_barrier(0);

    for(int t=0;t<NT;++t){
      COMPUTE(t&1);
      if(t+1<NT){
        __builtin_amdgcn_sched_barrier(0);
        __builtin_amdgcn_s_barrier();
        __builtin_amdgcn_sched_barrier(0);
        if(t+2<NT){
          STAGE(t&1, t+2);
          asm volatile("s_waitcnt vmcnt(10)" ::: "memory");
        }else{
          asm volatile("s_waitcnt vmcnt(0)" ::: "memory");
        }
        __builtin_amdgcn_s_barrier();
        __builtin_amdgcn_sched_barrier(0);
      }
    }

    #pragma unroll
    for(int mi=0;mi<4;++mi){
      #pragma unroll
      for(int cg=0;cg<2;++cg){
        const int col = x*64 + ((w&1)*2+cg)*16 + lr;
        const float bi=bias[col], bo=bias[col+512], bu=bias[col+1024];
        #pragma unroll
        for(int r=0;r<4;++r){
          const int mm=m0+wr+mi*16+lg*4+r;
          float iv=acc[mi][3*cg+0][r]+bi;
          float ov=acc[mi][3*cg+1][r]+bo;
          float uv=acc[mi][3*cg+2][r]+bu;
          float cn=sigm(iv)*ftanh(uv);
          float hn=sigm(ov)*ftanh(cn);
          const int tt=mm>>10, jj=mm-(tt<<10);
          const size_t nd=((size_t)tt*NPT+jj)*HD+col;
          cbuf[nd]=cn;
          h16[nd]=(f16)hn;
        }
      }
    }
  } else {
    // ---------- XWf: 128x128, K=768, NT=12 (f16 output) ----------
    char* Abase=sm;
    char* Bbase=sm+32768;
    int phys=(int)blockIdx.x-nbLeaf;
    int nb=(int)gridDim.x-nbLeaf;
    int xb, my;
    xcd_map(phys, nb, 4, xb, my);
    const int m0=my*128, n0=xb*128;
    const int NT=12;

    unsigned fofs[4];
    #pragma unroll
    for(int i=0;i<4;++i){
      int r=w*32+i*8+(lane>>3);
      int m=m0+r; if(m>=Mtot) m=Mtot-1;
      int t=m/NINT; int j=1024+(m-t*NINT);
      fofs[i]=(unsigned)(((size_t)t*NPT+j)*768);
    }
    unsigned bofs[4];
    #pragma unroll
    for(int i=0;i<4;++i){
      int r=n0+w*32+i*8+(lane>>3);
      bofs[i]=(unsigned)r*768u;
    }

    f32x4 acc[4][4];
    #pragma unroll
    for(int mi=0;mi<4;++mi)
      #pragma unroll
      for(int ni=0;ni<4;++ni) acc[mi][ni]=(f32x4){0.f,0.f,0.f,0.f};

    const int wr=(w>>1)*64, wc=(w&1)*64;

    auto STAGE=[&](int buf, int t){
      const unsigned ak=(unsigned)t*64u+swz;
      char* Ad=Abase+(size_t)buf*16384;
      #pragma unroll
      for(int i=0;i<4;++i)
        gll16(fx+fofs[i]+ak, Ad+(w*32+i*8)*128);
      char* Bd=Bbase+(size_t)buf*16384;
      #pragma unroll
      for(int i=0;i<4;++i)
        gll16(Wfc+bofs[i]+ak, Bd+(w*32+i*8)*128);
    };

    auto COMPUTE=[&](int cur){
      const char* Ab=Abase+(size_t)cur*16384;
      const char* Bb=Bbase+(size_t)cur*16384;
      #pragma unroll
      for(int ks=0;ks<2;++ks){
        const unsigned cb=((unsigned)(ks*64+lg*16)) ^ ((unsigned)(lr&7)<<4);
        f16x8 av[4], bv[4];
        #pragma unroll
        for(int mi=0;mi<4;++mi)
          av[mi]=*(const f16x8*)(Ab+(unsigned)(wr+mi*16+lr)*128u+cb);
        #pragma unroll
        for(int ni=0;ni<4;++ni)
          bv[ni]=*(const f16x8*)(Bb+(unsigned)((wc+ni*16)+lr)*128u+cb);
        __builtin_amdgcn_s_setprio(1);
        #pragma unroll
        for(int ni=0;ni<4;++ni)
          #pragma unroll
          for(int mi=0;mi<4;++mi)
            acc[mi][ni]=__builtin_amdgcn_mfma_f32_16x16x32_f16(av[mi],bv[ni],acc[mi][ni],0,0,0);
        __builtin_amdgcn_s_setprio(0);
      }
    };

    STAGE(0,0);
    STAGE(1,1);
    asm volatile("s_waitcnt vmcnt(8)" ::: "memory");
    __builtin_amdgcn_s_barrier();
    __builtin_amdgcn_sched_barrier(0);

    for(int t=0;t<NT;++t){
      COMPUTE(t&1);
      if(t+1<NT){
        __builtin_amdgcn_sched_barrier(0);
        __builtin_amdgcn_s_barrier();
        __builtin_amdgcn_sched_barrier(0);
        if(t+2<NT){
          STAGE(t&1, t+2);
          asm volatile("s_waitcnt vmcnt(8)" ::: "memory");
        }else{
          asm volatile("s_waitcnt vmcnt(0)" ::: "memory");
        }
        __builtin_amdgcn_s_barrier();
        __builtin_amdgcn_sched_barrier(0);
      }
    }

    #pragma unroll
    for(int mi=0;mi<4;++mi){
      #pragma unroll
      for(int ni=0;ni<4;++ni){
        const int col=n0+wc+ni*16+lr;
        #pragma unroll
        for(int r=0;r<4;++r){
          const int mm=m0+wr+mi*16+lg*4+r;
          if(mm<Mtot) XWf[(size_t)mm*512+col]=(f16)acc[mi][ni][r];
        }
      }
    }
  }
}

// ================= internal iou GEMM: 128 x 192, f16, XCD-chunked =================
__global__ __launch_bounds__(256,2)
void k_iou128p(const f16* __restrict__ fx, const f16* __restrict__ hs16,
               const f16* __restrict__ Wil, const float* __restrict__ bias,
               const f16* __restrict__ csum, f16* __restrict__ h16,
               float* __restrict__ cbuf,
               int start_n, int shift)
{
  extern __shared__ char sm[];                 // A: 2x16384, B: 2x24576
  char* Abase=sm;
  char* Bbase=sm+32768;
  const int tid=threadIdx.x;
  const int w=tid>>6, lane=tid&63;
  int x, my;
  xcd_map(blockIdx.x, gridDim.x, 8, x, my);
  const int m0=my*128;
  const int K=1280;
  const int NT=20;

  unsigned fofs[4], hofs[4];
  #pragma unroll
  for(int i=0;i<4;++i){
    int r=w*32+i*8+(lane>>3);
    int m=m0+r;
    int t_=m>>shift, j=m-(t_<<shift);
    fofs[i]=(unsigned)(((size_t)t_*NPT+start_n+j)*768);
    hofs[i]=(unsigned)m*512u;
  }
  unsigned bofs[6];
  #pragma unroll
  for(int i=0;i<6;++i){
    int r=x*192+w*48+i*8+(lane>>3);
    bofs[i]=(unsigned)r*(unsigned)K;
  }
  const unsigned swz=8u*((unsigned)(lane&7)^(unsigned)(lane>>3));

  f32x4 acc[4][6];
  #pragma unroll
  for(int mi=0;mi<4;++mi)
    #pragma unroll
    for(int ni=0;ni<6;++ni) acc[mi][ni]=(f32x4){0.f,0.f,0.f,0.f};

  const int wr=(w>>1)*64;
  const int wcF=(w&1)*6;
  const int lr=lane&15, lg=lane>>4;

  auto STAGE=[&](int buf, int t){
    const f16* base; int kt; bool useF;
    if(t<12){ base=fx;   kt=t;    useF=true;  }
    else    { base=hs16; kt=t-12; useF=false; }
    const unsigned kofs=(unsigned)kt*64u+swz;
    char* Ad=Abase+(size_t)buf*16384;
    #pragma unroll
    for(int i=0;i<4;++i){
      const f16* g=base+(useF?fofs[i]:hofs[i])+kofs;
      gll16(g, Ad+(w*32+i*8)*128);
    }
    const unsigned bk=(unsigned)t*64u+swz;
    char* Bd=Bbase+(size_t)buf*24576;
    #pragma unroll
    for(int i=0;i<6;++i){
      gll16(Wil+bofs[i]+bk, Bd+(w*48+i*8)*128);
    }
  };

  auto COMPUTE=[&](int cur){
    const char* Ab=Abase+(size_t)cur*16384;
    const char* Bb=Bbase+(size_t)cur*24576;
    #pragma unroll
    for(int ks=0;ks<2;++ks){
      const unsigned cb=((unsigned)(ks*64+lg*16)) ^ ((unsigned)(lr&7)<<4);
      f16x8 av[4], bv[6];
      #pragma unroll
      for(int mi=0;mi<4;++mi)
        av[mi]=*(const f16x8*)(Ab+(unsigned)(wr+mi*16+lr)*128u+cb);
      #pragma unroll
      for(int ni=0;ni<6;++ni)
        bv[ni]=*(const f16x8*)(Bb+(unsigned)((wcF+ni)*16+lr)*128u+cb);
      __builtin_amdgcn_s_setprio(1);
      #pragma unroll
      for(int ni=0;ni<6;++ni)
        #pragma unroll
        for(int mi=0;mi<4;++mi)
          acc[mi][ni]=__builtin_amdgcn_mfma_f32_16x16x32_f16(av[mi],bv[ni],acc[mi][ni],0,0,0);
      __builtin_amdgcn_s_setprio(0);
    }
  };

  STAGE(0,0);
  STAGE(1,1);
  asm volatile("s_waitcnt vmcnt(10)" ::: "memory");
  __builtin_amdgcn_s_barrier();
  __builtin_amdgcn_sched_barrier(0);

  for(int t=0;t<NT;++t){
    COMPUTE(t&1);
    if(t+1<NT){
      __builtin_amdgcn_sched_barrier(0);
      __builtin_amdgcn_s_barrier();
      __builtin_amdgcn_sched_barrier(0);
      if(t+2<NT){
        STAGE(t&1, t+2);
        asm volatile("s_waitcnt vmcnt(10)" ::: "memory");
      }else{
        asm volatile("s_waitcnt vmcnt(0)" ::: "memory");
      }
      __builtin_amdgcn_s_barrier();
      __builtin_amdgcn_sched_barrier(0);
    }
  }

  #pragma unroll
  for(int mi=0;mi<4;++mi){
    #pragma unroll
    for(int cg=0;cg<2;++cg){
      const int col = x*64 + ((w&1)*2+cg)*16 + lr;
      const float bi=bias[col], bo=bias[col+512], bu=bias[col+1024];
      #pragma unroll
      for(int r=0;r<4;++r){
        const int mm=m0+wr+mi*16+lg*4+r;
        float iv=acc[mi][3*cg+0][r]+bi;
        float ov=acc[mi][3*cg+1][r]+bo;
        float uv=acc[mi][3*cg+2][r]+bu;
        float cn=sigm(iv)*ftanh(uv);
        cn+=(float)csum[(size_t)mm*HD+col];
        float hn=sigm(ov)*ftanh(cn);
        const int tt=mm>>shift, jj=mm-(tt<<shift);
        const size_t nd=((size_t)tt*NPT+start_n+jj)*HD+col;
        cbuf[nd]=cn;
        h16[nd]=(f16)hn;
      }
    }
  }
}

// ---------------- old 64-tile iou (level 5 only, P=64; K=1280 gate-major layout, f16) ----------------
__global__ __launch_bounds__(256)
void k_iou(const f16* __restrict__ fx, const f16* __restrict__ hs16,
           const f16* __restrict__ Wcat, const float* __restrict__ bias,
           const f16* __restrict__ csum, f16* __restrict__ h16,
           float* __restrict__ cbuf,
           int start_n, int shift, int K, int KB)
{
  __shared__ f16 As[64][40];
  __shared__ f16 Bs[3][64][40];
  const int tid=threadIdx.x;
  const int m0=blockIdx.x*64, n0=blockIdx.y*64;
  const int srow=tid>>2, skc=(tid&3)*8;
  const int m=m0+srow;
  const int t=m>>shift, j=m-(t<<shift);
  const size_t frow=((size_t)t*NPT+start_n+j)*768;
  const f16* aF=fx+frow;
  const f16* aH=hs16+(size_t)m*HD;
  const f16* bp0=Wcat+(size_t)(n0+srow)*KB;
  const f16* bp1=Wcat+(size_t)(512+n0+srow)*KB;
  const f16* bp2=Wcat+(size_t)(1024+n0+srow)*KB;

  f32x4 acc[3][2][2];
  #pragma unroll
  for(int g=0;g<3;++g)
    #pragma unroll
    for(int mi=0;mi<2;++mi)
      #pragma unroll
      for(int ni=0;ni<2;++ni) acc[g][mi][ni]=(f32x4){0.f,0.f,0.f,0.f};

  const int w=tid>>6, lane=tid&63;
  const int wr=(w>>1)*32, wc=(w&1)*32;
  const int lr=lane&15, lg=lane>>4;

  for(int k0=0;k0<K;k0+=32){
    const f16* ap = (k0<768)? (aF+k0) : (aH+(k0-768));
    *(f16x8*)&As[srow][skc]=*(const f16x8*)(ap+skc);
    *(f16x8*)&Bs[0][srow][skc]=*(const f16x8*)(bp0+k0+skc);
    *(f16x8*)&Bs[1][srow][skc]=*(const f16x8*)(bp1+k0+skc);
    *(f16x8*)&Bs[2][srow][skc]=*(const f16x8*)(bp2+k0+skc);
    __syncthreads();
    f16x8 a0=*(f16x8*)&As[wr+lr][lg*8];
    f16x8 a1=*(f16x8*)&As[wr+16+lr][lg*8];
    #pragma unroll
    for(int g=0;g<3;++g){
      #pragma unroll
      for(int ni=0;ni<2;++ni){
        f16x8 bv=*(f16x8*)&Bs[g][wc+ni*16+lr][lg*8];
        acc[g][0][ni]=__builtin_amdgcn_mfma_f32_16x16x32_f16(a0,bv,acc[g][0][ni],0,0,0);
        acc[g][1][ni]=__builtin_amdgcn_mfma_f32_16x16x32_f16(a1,bv,acc[g][1][ni],0,0,0);
      }
    }
    __syncthreads();
  }

  #pragma unroll
  for(int mi=0;mi<2;++mi){
    #pragma unroll
    for(int ni=0;ni<2;++ni){
      const int col=n0+wc+ni*16+lr;
      const float bi=bias[col], bo=bias[col+512], bu=bias[col+1024];
      #pragma unroll
      for(int r=0;r<4;++r){
        const int mm=m0+wr+mi*16+lg*4+r;
        float iv=acc[0][mi][ni][r]+bi;
        float ov=acc[1][mi][ni][r]+bo;
        float uv=acc[2][mi][ni][r]+bu;
        float cn=sigm(iv)*ftanh(uv);
        cn+=(float)csum[(size_t)mm*HD+col];
        float hn=sigm(ov)*ftanh(cn);
        const int tt=mm>>shift, jj=mm-(tt<<shift);
        const size_t nd=((size_t)tt*NPT+start_n+jj)*HD+col;
        cbuf[nd]=cn;
        h16[nd]=(f16)hn;
      }
    }
  }
}

// ================= Uh forget-gate: pipelined 128x128 (NT=8, f16) + fused csum/hsum =================
__global__ __launch_bounds__(256,2)
void k_uh128p(const f16* __restrict__ h16,
              const f16* __restrict__ Ufc, const float* __restrict__ bias,
              const f16* __restrict__ XWf, const float* __restrict__ cbuf,
              f16* __restrict__ csum, f16* __restrict__ hs16,
              int start_ch, int lc, int xwoff)
{
  extern __shared__ char sm[];     // A: 2x16384, B: 2x16384
  char* Abase=sm;
  char* Bbase=sm+32768;
  const int tid=threadIdx.x;
  const int w=tid>>6, lane=tid&63;
  int xb, my;
  xcd_map(blockIdx.x, gridDim.x, 4, xb, my);
  const int e0=my*128, n0=xb*128;
  const int NT=8;

  unsigned hofs[4];
  #pragma unroll
  for(int i=0;i<4;++i){
    int r=w*32+i*8+(lane>>3);
    int e=e0+r;
    int t=e>>lc, ei=e-(t<<lc);
    hofs[i]=(unsigned)(((size_t)t*NPT+start_ch+ei)*HD);
  }
  unsigned bofs[4];
  #pragma unroll
  for(int i=0;i<4;++i){
    int r=n0+w*32+i*8+(lane>>3);
    bofs[i]=(unsigned)r*512u;
  }
  const unsigned swz=8u*((unsigned)(lane&7)^(unsigned)(lane>>3));

  f32x4 acc[4][4];
  #pragma unroll
  for(int mi=0;mi<4;++mi)
    #pragma unroll
    for(int ni=0;ni<4;++ni) acc[mi][ni]=(f32x4){0.f,0.f,0.f,0.f};

  const int wr=(w>>1)*64, wc=(w&1)*64;
  const int lr=lane&15, lg=lane>>4;

  auto STAGE=[&](int buf, int t){
    const unsigned ak=(unsigned)t*64u+swz;
    char* Ad=Abase+(size_t)buf*16384;
    #pragma unroll
    for(int i=0;i<4;++i)
      gll16(h16+hofs[i]+ak, Ad+(w*32+i*8)*128);
    char* Bd=Bbase+(size_t)buf*16384;
    #pragma unroll
    for(int i=0;i<4;++i)
      gll16(Ufc+bofs[i]+ak, Bd+(w*32+i*8)*128);
  };

  auto COMPUTE=[&](int cur){
    const char* Ab=Abase+(size_t)cur*16384;
    const char* Bb=Bbase+(size_t)cur*16384;
    #pragma unroll
    for(int ks=0;ks<2;++ks){
      const unsigned cb=((unsigned)(ks*64+lg*16)) ^ ((unsigned)(lr&7)<<4);
      f16x8 av[4], bv[4];
      #pragma unroll
      for(int mi=0;mi<4;++mi)
        av[mi]=*(const f16x8*)(Ab+(unsigned)(wr+mi*16+lr)*128u+cb);
      #pragma unroll
      for(int ni=0;ni<4;++ni)
        bv[ni]=*(const f16x8*)(Bb+(unsigned)((wc+ni*16)+lr)*128u+cb);
      __builtin_amdgcn_s_setprio(1);
      #pragma unroll
      for(int ni=0;ni<4;++ni)
        #pragma unroll
        for(int mi=0;mi<4;++mi)
          acc[mi][ni]=__builtin_amdgcn_mfma_f32_16x16x32_f16(av[mi],bv[ni],acc[mi][ni],0,0,0);
      __builtin_amdgcn_s_setprio(0);
    }
  };

  STAGE(0,0);
  STAGE(1,1);
  asm volatile("s_waitcnt vmcnt(8)" ::: "memory");
  __builtin_amdgcn_s_barrier();
  __builtin_amdgcn_sched_barrier(0);

  for(int t=0;t<NT;++t){
    COMPUTE(t&1);
    if(t+1<NT){
      __builtin_amdgcn_sched_barrier(0);
      __builtin_amdgcn_s_barrier();
      __builtin_amdgcn_sched_barrier(0);
      if(t+2<NT){
        STAGE(t&1, t+2);
        asm volatile("s_waitcnt vmcnt(8)" ::: "memory");
      }else{
        asm volatile("s_waitcnt vmcnt(0)" ::: "memory");
      }
      __builtin_amdgcn_s_barrier();
      __builtin_amdgcn_sched_barrier(0);
    }
  }

  #pragma unroll
  for(int mi=0;mi<4;++mi){
    const int ebase=e0+wr+mi*16+lg*4;
    const int tt=ebase>>lc, eib=ebase-(tt<<lc);
    const int inode=tt*NINT + xwoff + (eib>>2);
    const int par=ebase>>2;
    #pragma unroll
    for(int ni=0;ni<4;++ni){
      const int col=n0+wc+ni*16+lr;
      const float base=bias[col]+(float)XWf[(size_t)inode*512+col];
      const size_t chbase=((size_t)tt*NPT+start_ch+eib)*HD+col;
      float s=0.f, hsv=0.f;
      #pragma unroll
      for(int r=0;r<4;++r){
        const size_t ci=chbase+(size_t)r*HD;
        float fv=sigm(acc[mi][ni][r]+base);
        s+=fv*cbuf[ci];
        hsv+=(float)h16[ci];
      }
      csum[(size_t)par*HD+col]=(f16)s;
      hs16[(size_t)par*HD+col]=(f16)hsv;
    }
  }
}

// ---------------- final heads: h_st softmax (+root blocks appended) ----------------
__global__ __launch_bounds__(256)
void k_final2(const f16* __restrict__ h16,
              const float* __restrict__ Wy, const float* __restrict__ gamma,
              const float* __restrict__ beta, float* __restrict__ out0,
              const float* __restrict__ Wff, float* __restrict__ out1,
              int Nn, int nbMain)
{
  const int tid=threadIdx.x;
  if((int)blockIdx.x < nbMain){
    const int gtid=blockIdx.x*256+tid;
    const int node=gtid>>6, lane=gtid&63;
    if(node>=Nn) return;
    const size_t base=(size_t)node*HD+lane*8;
    f16x8 hv=*(const f16x8*)(h16+base);
    float hf[8];
    #pragma unroll
    for(int e=0;e<8;++e) hf[e]=(float)hv[e];
    float y[4];
    #pragma unroll
    for(int jj=0;jj<4;++jj){
      const float* wp=Wy+jj*HD+lane*8;
      float s=0.f;
      #pragma unroll
      for(int e=0;e<8;++e) s+=hf[e]*wp[e];
      #pragma unroll
      for(int off=32;off>=1;off>>=1) s+=__shfl_xor(s,off,64);
      y[jj]=s;
    }
    if(lane==0){
      float mu=0.25f*(y[0]+y[1]+y[2]+y[3]);
      float var=0.f;
      #pragma unroll
      for(int jj=0;jj<4;++jj){ float d=y[jj]-mu; var+=d*d; }
      var*=0.25f;
      float rs=rsqrtf(var+1e-6f);
      float z[4], zmax=-1e30f;
      #pragma unroll
      for(int jj=0;jj<4;++jj){ z[jj]=(y[jj]-mu)*rs*gamma[jj]+beta[jj]; zmax=fmaxf(zmax,z[jj]); }
      float es=0.f;
      #pragma unroll
      for(int jj=0;jj<4;++jj){ z[jj]=__expf(z[jj]-zmax); es+=z[jj]; }
      float inv=frcp(es);
      #pragma unroll
      for(int jj=0;jj<4;++jj) out0[(size_t)node*4+jj]=z[jj]*inv;
    }
  } else {
    const int gtid=((int)blockIdx.x-nbMain)*256+tid;
    const int tt=gtid>>6, lane=gtid&63;
    if(tt>=64) return;
    const size_t base=((size_t)tt*NPT+1364)*HD+lane*8;
    f16x8 hv=*(const f16x8*)(h16+base);
    float hf[8];
    #pragma unroll
    for(int e=0;e<8;++e) hf[e]=(float)hv[e];
    float y[4];
    #pragma unroll
    for(int jj=0;jj<4;++jj){
      const float* wp=Wff+jj*HD+lane*8;
      float s=0.f;
      #pragma unroll
      for(int e=0;e<8;++e) s+=hf[e]*wp[e];
      #pragma unroll
      for(int off=32;off>=1;off>>=1) s+=__shfl_xor(s,off,64);
      y[jj]=s;
    }
    if(lane==0){
      float zmax=fmaxf(fmaxf(y[0],y[1]),fmaxf(y[2],y[3]));
      float es=0.f, z[4];
      #pragma unroll
      for(int jj=0;jj<4;++jj){ z[jj]=__expf(y[jj]-zmax); es+=z[jj]; }
      float inv=frcp(es);
      #pragma unroll
      for(int jj=0;jj<4;++jj) out1[(size_t)tt*4+jj]=z[jj]*inv;
    }
  }
}

extern "C" void kernel_launch(void* const* d_in, const int* in_sizes, int n_in,
                              void* d_out, int out_size, void* d_ws, size_t ws_size,
                              hipStream_t stream)
{
  const float* features=(const float*)d_in[0];
  const float* W_iou=(const float*)d_in[6];
  const float* b_iou=(const float*)d_in[7];
  const float* U_iou=(const float*)d_in[8];
  const float* W_f  =(const float*)d_in[9];
  const float* b_f  =(const float*)d_in[10];
  const float* U_f  =(const float*)d_in[11];
  const float* W_ff =(const float*)d_in[12];
  const float* W_sd =(const float*)d_in[13];
  const float* W_sd2=(const float*)d_in[14];
  const float* W_sf =(const float*)d_in[15];
  const float* ln_g =(const float*)d_in[16];
  const float* ln_b =(const float*)d_in[17];

  const int N=in_sizes[0]/768;   // 87360
  const int T=N/NPT;             // 64
  const int MINT=T*NINT;         // 21824

  float* out0=(float*)d_out;
  float* out1=out0+(size_t)N*4;
  float* cbuf=out1+(size_t)T*4;  // c output region (live c-state)

  char* p=(char*)d_ws;
  auto alloc=[&](size_t bytes){ char* r=p; p+=((bytes+255)&~(size_t)255); return r; };
  f16*   fx   =(f16*)  alloc((size_t)N*768*2);
  f16*   hs16 =(f16*)  alloc((size_t)16384*HD*2);
  f16*   csum =(f16*)  alloc((size_t)16384*HD*2);
  f16*   h16  =(f16*)  alloc((size_t)N*HD*2);
  f16*   WilL =(f16*)  alloc((size_t)1536*768*2);
  f16*   WilI =(f16*)  alloc((size_t)1536*1280*2);
  f16*   Wcat2=(f16*)  alloc((size_t)1536*1280*2);   // level-5 64-tile layout
  f16*   Wfc  =(f16*)  alloc((size_t)512*768*2);
  f16*   Ufc  =(f16*)  alloc((size_t)512*512*2);
  float* tmp4 =(float*)alloc((size_t)4*1024*4);
  float* Wy   =(float*)alloc((size_t)4*512*4);
  f16*   XWf  =(f16*)  alloc((size_t)MINT*512*2);

  // fused prep (all elementwise conversions + tmp4), then Wy
  {
    size_t nfeat8=(size_t)N*768/8;
    size_t tot=nfeat8+(size_t)1536*768/8+(size_t)1536*1280/8*2+(size_t)512*768/8+(size_t)512*512/8+4096;
    int nb=(int)((tot+255)/256);
    k_prep<<<nb,256,0,stream>>>(features,W_iou,U_iou,W_f,U_f,W_sf,W_sd2,
                                fx,WilL,WilI,Wcat2,Wfc,Ufc,tmp4,nfeat8);
  }
  { k_wy2<<<8,256,0,stream>>>(W_sf,tmp4,W_sd,Wy); }

  static const int starts[6]={0,1024,1280,1344,1360,1364};
  static const int csh[6]  ={10,8,6,4,2,0};
  static const int counts[6]={1024,256,64,16,4,1};
  static const int xwoffs[6]={0,0,256,320,336,340};

  // fused leaf iou + XWf (independent, one launch)
  {
    int nbLeaf=8*((T*1024)/128);             // 4096
    int nbXwf=4*((MINT+127)/128);            // 684
    k_leafxwf<<<nbLeaf+nbXwf,256,IOU_LDS,stream>>>(fx,WilL,b_iou,h16,cbuf,Wfc,XWf,nbLeaf,MINT);
  }

  for(int n=1;n<6;++n){
    int P=T*counts[n], E=T*counts[n-1];
    { int nb=4*(E/128);
      k_uh128p<<<nb,256,G128_LDS,stream>>>(h16,Ufc,b_f,XWf,cbuf,csum,hs16,
                                           starts[n-1],csh[n-1],xwoffs[n]); }
    if(P>=128){
      int nb=8*(P/128);
      k_iou128p<<<nb,256,IOU_LDS,stream>>>(fx,hs16,WilI,b_iou,csum,h16,cbuf,starts[n],csh[n]);
    }else{
      dim3 g(P/64,8);
      k_iou<<<g,256,0,stream>>>(fx,hs16,Wcat2,b_iou,csum,h16,cbuf,starts[n],csh[n],1280,1280);
    }
  }

  // heads (stance folded into Wy; root appended to final2 launch)
  {
    int nbMain=(N*64+255)/256;
    k_final2<<<nbMain+16,256,0,stream>>>(h16,Wy,ln_g,ln_b,out0,W_ff,out1,N,nbMain);
  }
}